// Round 1
// baseline (1054.226 us; speedup 1.0000x reference)
//
#include <hip/hip_runtime.h>
#include <hip/hip_bf16.h>

#define NEG 0.2f

// ---------------------------------------------------------------------------
// K1: h = x @ proj_w + proj_b  (N x 128) and the four per-node alpha dots.
// Block 256 = 8 nodes/iter, 32 threads/node, 4 cols (float4) each.
// ---------------------------------------------------------------------------
__global__ __launch_bounds__(256) void proj_kernel(
    const float* __restrict__ x, const float* __restrict__ pw,
    const float* __restrict__ pb,
    const float* __restrict__ ls0, const float* __restrict__ ld0,
    const float* __restrict__ ls1, const float* __restrict__ ld1,
    float* __restrict__ h, float* __restrict__ as0, float* __restrict__ ad0,
    float* __restrict__ as1, float* __restrict__ ad1, int N)
{
    __shared__ float4 Ws[128][32];   // 64 KB
    __shared__ float  Xs[8][128];    // 4 KB
    __shared__ float  lin[4][128];   // 2 KB  (src0,dst0,src1,dst1 as [8][16] flat)
    __shared__ float  bsh[128];
    int t = threadIdx.x;
    for (int i = t; i < 4096; i += 256) {
        int r = i >> 5, c = i & 31;
        Ws[r][c] = reinterpret_cast<const float4*>(pw)[i];
    }
    for (int i = t; i < 128; i += 256) {
        lin[0][i] = ls0[i]; lin[1][i] = ld0[i];
        lin[2][i] = ls1[i]; lin[3][i] = ld1[i];
        bsh[i] = pb[i];
    }
    int ln = t >> 5, tg = t & 31;
    int head = tg >> 2, dbase = (tg & 3) * 4;
    int ngroups = (N + 7) >> 3;
    for (int g = blockIdx.x; g < ngroups; g += gridDim.x) {
        int n0 = g << 3;
        __syncthreads();
        {
            int i = t;  // 256 float4 = 8 rows x 128 floats
            int r = i >> 5, c = i & 31; int n = n0 + r;
            float4 v = make_float4(0.f, 0.f, 0.f, 0.f);
            if (n < N) v = reinterpret_cast<const float4*>(x)[(size_t)n * 32 + c];
            reinterpret_cast<float4*>(&Xs[0][0])[i] = v;
        }
        __syncthreads();
        int n = n0 + ln;
        float4 acc = make_float4(0.f, 0.f, 0.f, 0.f);
        #pragma unroll 8
        for (int k = 0; k < 128; ++k) {
            float xv = Xs[ln][k];
            float4 w = Ws[k][tg];
            acc.x = fmaf(xv, w.x, acc.x); acc.y = fmaf(xv, w.y, acc.y);
            acc.z = fmaf(xv, w.z, acc.z); acc.w = fmaf(xv, w.w, acc.w);
        }
        float4 b4 = reinterpret_cast<const float4*>(bsh)[tg];
        acc.x += b4.x; acc.y += b4.y; acc.z += b4.z; acc.w += b4.w;
        if (n < N) reinterpret_cast<float4*>(h)[(size_t)n * 32 + tg] = acc;
        float* outs[4] = {as0, ad0, as1, ad1};
        #pragma unroll
        for (int s = 0; s < 4; ++s) {
            const float* lv = &lin[s][head * 16 + dbase];
            float p = acc.x * lv[0] + acc.y * lv[1] + acc.z * lv[2] + acc.w * lv[3];
            p += __shfl_xor(p, 1);
            p += __shfl_xor(p, 2);
            if ((tg & 3) == 0 && n < N) outs[s][n * 8 + head] = p;
        }
    }
}

// ---------------------------------------------------------------------------
// CSR build: histogram of dst, exclusive scan, fill perm with src ids.
// ---------------------------------------------------------------------------
__global__ __launch_bounds__(256) void hist_kernel(
    const int* __restrict__ ei, int E, int* __restrict__ deg)
{
    int i = blockIdx.x * blockDim.x + threadIdx.x;
    int stride = gridDim.x * blockDim.x;
    for (int e = i; e < E; e += stride) {
        int d = ei[E + e];
        atomicAdd(&deg[d], 1);
    }
}

__global__ __launch_bounds__(256) void scan1_kernel(
    const int* __restrict__ in, int* __restrict__ out, int* __restrict__ bsums, int n)
{
    __shared__ int sh[256];
    int t = threadIdx.x;
    int i = blockIdx.x * 256 + t;
    int v = (i < n) ? in[i] : 0;
    sh[t] = v;
    __syncthreads();
    for (int ofs = 1; ofs < 256; ofs <<= 1) {
        int xv = (t >= ofs) ? sh[t - ofs] : 0;
        __syncthreads();
        sh[t] += xv;
        __syncthreads();
    }
    if (i < n) out[i] = sh[t] - v;          // exclusive
    if (t == 255) bsums[blockIdx.x] = sh[255];
}

__global__ __launch_bounds__(512) void scan2_kernel(int* __restrict__ bs, int nb)
{
    __shared__ int sh[512];
    int t = threadIdx.x;
    int v = (t < nb) ? bs[t] : 0;
    sh[t] = v;
    __syncthreads();
    for (int ofs = 1; ofs < 512; ofs <<= 1) {
        int xv = (t >= ofs) ? sh[t - ofs] : 0;
        __syncthreads();
        sh[t] += xv;
        __syncthreads();
    }
    if (t < nb) bs[t] = sh[t] - v;          // exclusive
}

__global__ __launch_bounds__(256) void scan3_kernel(
    int* __restrict__ out, const int* __restrict__ bs, int n)
{
    int i = blockIdx.x * 256 + threadIdx.x;
    if (i < n) out[i] += bs[blockIdx.x];
}

__global__ __launch_bounds__(256) void fill_kernel(
    const int* __restrict__ ei, int E, const int* __restrict__ off,
    int* __restrict__ cur, int* __restrict__ perm)
{
    int i = blockIdx.x * blockDim.x + threadIdx.x;
    int stride = gridDim.x * blockDim.x;
    for (int e = i; e < E; e += stride) {
        int s = ei[e];
        int d = ei[E + e];
        int p = atomicAdd(&cur[d], 1);
        perm[off[d] + p] = s;
    }
}

// ---------------------------------------------------------------------------
// K3: per-destination-node aggregation (one 64-lane wave per node).
// loop1: softmax denominator (8 edges x 8 heads in parallel).
// loop2: out[v] += h[src] * exp(lrelu(.))/s  (lane owns 2 of 128 dims).
// segment_max skipped: alpha bounded (|alpha|<~3), exp is safe; softmax is
// shift-invariant so result is identical up to fp rounding.
// ---------------------------------------------------------------------------
__global__ __launch_bounds__(256) void agg_kernel(
    const int* __restrict__ off, const int* __restrict__ perm,
    const float* __restrict__ asrc, const float* __restrict__ adst,
    const float* __restrict__ h, float* __restrict__ outm, int N)
{
    int wid = blockIdx.x * (blockDim.x >> 6) + (threadIdx.x >> 6);
    int lane = threadIdx.x & 63;
    if (wid >= N) return;
    int start = off[wid], end = off[wid + 1];
    int hh = lane & 7;    // head, loop1
    int h2 = lane >> 3;   // head owning dims 2*lane, 2*lane+1
    float av1 = adst[wid * 8 + hh];
    float av2 = adst[wid * 8 + h2];
    float ssum = 0.f;
    for (int i = start + h2; i < end; i += 8) {
        int s = perm[i];
        float al = asrc[s * 8 + hh] + av1;
        al = al > 0.f ? al : NEG * al;
        ssum += __expf(al);
    }
    ssum += __shfl_xor(ssum, 8);
    ssum += __shfl_xor(ssum, 16);
    ssum += __shfl_xor(ssum, 32);
    float sv = __shfl(ssum, h2);          // lane h2 holds head h2's sum
    float inv = 1.f / (sv + 1e-16f);
    float acc0 = 0.f, acc1 = 0.f;
    for (int i = start; i < end; ++i) {
        int s = perm[i];
        float al = asrc[s * 8 + h2] + av2;
        al = al > 0.f ? al : NEG * al;
        float a = __expf(al) * inv;
        float2 hv = reinterpret_cast<const float2*>(h)[(size_t)s * 64 + lane];
        acc0 = fmaf(hv.x, a, acc0);
        acc1 = fmaf(hv.y, a, acc1);
    }
    float2 o;
    o.x = acc0 > 0.f ? acc0 : 0.f;
    o.y = acc1 > 0.f ? acc1 : 0.f;
    reinterpret_cast<float2*>(outm)[(size_t)wid * 64 + lane] = o;
}

// ---------------------------------------------------------------------------
// K4: semantic-attention scores (block-local partial sums, no hot atomics).
// ---------------------------------------------------------------------------
__global__ __launch_bounds__(256) void score_kernel(
    const float* __restrict__ o0, const float* __restrict__ o1,
    const float* __restrict__ kw, const float* __restrict__ kb,
    const float* __restrict__ q, float* __restrict__ partials, int N)
{
    __shared__ float4 Ws[128][32];
    __shared__ float  Xs[8][128];
    __shared__ float  kbs[128];
    __shared__ float  qs[128];
    __shared__ float  red[256];
    int t = threadIdx.x;
    for (int i = t; i < 4096; i += 256) {
        int r = i >> 5, c = i & 31;
        Ws[r][c] = reinterpret_cast<const float4*>(kw)[i];
    }
    for (int i = t; i < 128; i += 256) { kbs[i] = kb[i]; qs[i] = q[i]; }
    int ln = t >> 5, tg = t & 31;
    int ngpm = (N + 7) >> 3;
    float bs0 = 0.f, bs1 = 0.f;
    for (int g = blockIdx.x; g < 2 * ngpm; g += gridDim.x) {
        int m = (g >= ngpm);
        const float* om = m ? o1 : o0;
        int n0 = (g - m * ngpm) << 3;
        __syncthreads();
        {
            int i = t;
            int r = i >> 5, c = i & 31; int n = n0 + r;
            float4 v = make_float4(0.f, 0.f, 0.f, 0.f);
            if (n < N) v = reinterpret_cast<const float4*>(om)[(size_t)n * 32 + c];
            reinterpret_cast<float4*>(&Xs[0][0])[i] = v;
        }
        __syncthreads();
        int n = n0 + ln;
        float4 acc = reinterpret_cast<const float4*>(kbs)[tg];
        #pragma unroll 8
        for (int k = 0; k < 128; ++k) {
            float xv = Xs[ln][k];
            float4 w = Ws[k][tg];
            acc.x = fmaf(xv, w.x, acc.x); acc.y = fmaf(xv, w.y, acc.y);
            acc.z = fmaf(xv, w.z, acc.z); acc.w = fmaf(xv, w.w, acc.w);
        }
        float4 q4 = reinterpret_cast<const float4*>(qs)[tg];
        float p = q4.x * tanhf(acc.x) + q4.y * tanhf(acc.y)
                + q4.z * tanhf(acc.z) + q4.w * tanhf(acc.w);
        if (n >= N) p = 0.f;
        if (m) bs1 += p; else bs0 += p;
    }
    __syncthreads();
    red[t] = bs0; __syncthreads();
    for (int o = 128; o > 0; o >>= 1) {
        if (t < o) red[t] += red[t + o];
        __syncthreads();
    }
    if (t == 0) partials[blockIdx.x * 2] = red[0];
    __syncthreads();
    red[t] = bs1; __syncthreads();
    for (int o = 128; o > 0; o >>= 1) {
        if (t < o) red[t] += red[t + o];
        __syncthreads();
    }
    if (t == 0) partials[blockIdx.x * 2 + 1] = red[0];
}

__global__ __launch_bounds__(256) void beta_kernel(
    const float* __restrict__ partials, int G, float invN, float* __restrict__ beta)
{
    __shared__ float r0[256], r1[256];
    int t = threadIdx.x;
    float s0 = 0.f, s1 = 0.f;
    for (int i = t; i < G; i += 256) { s0 += partials[i * 2]; s1 += partials[i * 2 + 1]; }
    r0[t] = s0; r1[t] = s1; __syncthreads();
    for (int o = 128; o > 0; o >>= 1) {
        if (t < o) { r0[t] += r0[t + o]; r1[t] += r1[t + o]; }
        __syncthreads();
    }
    if (t == 0) {
        float a = r0[0] * invN, b = r1[0] * invN;
        float mx = fmaxf(a, b);
        float ea = __expf(a - mx), eb = __expf(b - mx);
        float inv = 1.f / (ea + eb);
        beta[0] = ea * inv; beta[1] = eb * inv;
    }
}

// ---------------------------------------------------------------------------
// K6: y = (b0*out0 + b1*out1) @ out_w + out_b
// ---------------------------------------------------------------------------
__global__ __launch_bounds__(256) void final_kernel(
    const float* __restrict__ o0, const float* __restrict__ o1,
    const float* __restrict__ beta, const float* __restrict__ ow,
    const float* __restrict__ ob, float* __restrict__ y, int N)
{
    __shared__ float4 Ws[128][16];   // 32 KB
    __shared__ float  Xs[16][128];   // 8 KB
    __shared__ float  obs[64];
    int t = threadIdx.x;
    for (int i = t; i < 2048; i += 256) {
        int r = i >> 4, c = i & 15;
        Ws[r][c] = reinterpret_cast<const float4*>(ow)[i];
    }
    if (t < 64) obs[t] = ob[t];
    float b0 = beta[0], b1 = beta[1];
    int ln = t >> 4, tg = t & 15;
    int ngroups = (N + 15) >> 4;
    for (int g = blockIdx.x; g < ngroups; g += gridDim.x) {
        int n0 = g << 4;
        __syncthreads();
        for (int i = t; i < 512; i += 256) {
            int r = i >> 5, c = i & 31; int n = n0 + r;
            float4 v = make_float4(0.f, 0.f, 0.f, 0.f);
            if (n < N) {
                float4 a = reinterpret_cast<const float4*>(o0)[(size_t)n * 32 + c];
                float4 b = reinterpret_cast<const float4*>(o1)[(size_t)n * 32 + c];
                v.x = b0 * a.x + b1 * b.x; v.y = b0 * a.y + b1 * b.y;
                v.z = b0 * a.z + b1 * b.z; v.w = b0 * a.w + b1 * b.w;
            }
            reinterpret_cast<float4*>(&Xs[0][0])[i] = v;
        }
        __syncthreads();
        int n = n0 + ln;
        float4 acc = reinterpret_cast<const float4*>(obs)[tg];
        #pragma unroll 8
        for (int k = 0; k < 128; ++k) {
            float xv = Xs[ln][k];
            float4 w = Ws[k][tg];
            acc.x = fmaf(xv, w.x, acc.x); acc.y = fmaf(xv, w.y, acc.y);
            acc.z = fmaf(xv, w.z, acc.z); acc.w = fmaf(xv, w.w, acc.w);
        }
        if (n < N) reinterpret_cast<float4*>(y)[(size_t)n * 16 + tg] = acc;
    }
}

// ---------------------------------------------------------------------------
extern "C" void kernel_launch(void* const* d_in, const int* in_sizes, int n_in,
                              void* d_out, int out_size, void* d_ws, size_t ws_size,
                              hipStream_t stream)
{
    const float* x   = (const float*)d_in[0];
    const int*   ei0 = (const int*)d_in[1];
    const int*   ei1 = (const int*)d_in[2];
    const float* pw  = (const float*)d_in[3];
    const float* pb  = (const float*)d_in[4];
    const float* ls0 = (const float*)d_in[5];
    const float* ld0 = (const float*)d_in[6];
    const float* ls1 = (const float*)d_in[7];
    const float* ld1 = (const float*)d_in[8];
    const float* kw  = (const float*)d_in[9];
    const float* kb  = (const float*)d_in[10];
    const float* q   = (const float*)d_in[11];
    const float* ow  = (const float*)d_in[12];
    const float* ob  = (const float*)d_in[13];
    int N  = in_sizes[0] / 128;
    int E0 = in_sizes[1] / 2;
    int E1 = in_sizes[2] / 2;

    char* w = (char*)d_ws;
    size_t o = 0;
    auto alloc = [&](size_t bytes) -> void* {
        void* p = w + o;
        o += (bytes + 255) & ~(size_t)255;
        return p;
    };
    float* h    = (float*)alloc((size_t)N * 128 * 4);
    float* as0  = (float*)alloc((size_t)N * 8 * 4);
    float* ad0  = (float*)alloc((size_t)N * 8 * 4);
    float* as1  = (float*)alloc((size_t)N * 8 * 4);
    float* ad1  = (float*)alloc((size_t)N * 8 * 4);
    float* out0 = (float*)alloc((size_t)N * 128 * 4);
    float* out1 = (float*)alloc((size_t)N * 128 * 4);
    char*  zbase = w + o;                       // contiguous zeroed region
    int* deg0 = (int*)alloc((size_t)(N + 1) * 4);
    int* cur0 = (int*)alloc((size_t)N * 4);
    int* deg1 = (int*)alloc((size_t)(N + 1) * 4);
    int* cur1 = (int*)alloc((size_t)N * 4);
    size_t zbytes = (w + o) - zbase;
    int* off0 = (int*)alloc((size_t)(N + 1) * 4);
    int* off1 = (int*)alloc((size_t)(N + 1) * 4);
    int* bsums = (int*)alloc(1024 * 4);
    int* perm0 = (int*)alloc((size_t)E0 * 4);
    int* perm1 = (int*)alloc((size_t)E1 * 4);
    float* partials = (float*)alloc((size_t)2 * 2048 * 4);
    float* beta = (float*)alloc(256);

    hipMemsetAsync(zbase, 0, zbytes, stream);

    proj_kernel<<<1024, 256, 0, stream>>>(x, pw, pb, ls0, ld0, ls1, ld1,
                                          h, as0, ad0, as1, ad1, N);

    hist_kernel<<<2048, 256, 0, stream>>>(ei0, E0, deg0);
    hist_kernel<<<2048, 256, 0, stream>>>(ei1, E1, deg1);

    int n1 = N + 1;
    int nb = (n1 + 255) / 256;
    scan1_kernel<<<nb, 256, 0, stream>>>(deg0, off0, bsums, n1);
    scan2_kernel<<<1, 512, 0, stream>>>(bsums, nb);
    scan3_kernel<<<nb, 256, 0, stream>>>(off0, bsums, n1);
    scan1_kernel<<<nb, 256, 0, stream>>>(deg1, off1, bsums, n1);
    scan2_kernel<<<1, 512, 0, stream>>>(bsums, nb);
    scan3_kernel<<<nb, 256, 0, stream>>>(off1, bsums, n1);

    fill_kernel<<<2048, 256, 0, stream>>>(ei0, E0, off0, cur0, perm0);
    fill_kernel<<<2048, 256, 0, stream>>>(ei1, E1, off1, cur1, perm1);

    int aggBlocks = (N + 3) / 4;
    agg_kernel<<<aggBlocks, 256, 0, stream>>>(off0, perm0, as0, ad0, h, out0, N);
    agg_kernel<<<aggBlocks, 256, 0, stream>>>(off1, perm1, as1, ad1, h, out1, N);

    const int SG = 1024;
    score_kernel<<<SG, 256, 0, stream>>>(out0, out1, kw, kb, q, partials, N);
    beta_kernel<<<1, 256, 0, stream>>>(partials, SG, 1.0f / (float)N, beta);
    final_kernel<<<1024, 256, 0, stream>>>(out0, out1, beta, ow, ob, (float*)d_out, N);
}

// Round 6
// 916.083 us; speedup vs baseline: 1.1508x; 1.1508x over previous
//
#include <hip/hip_runtime.h>
#include <hip/hip_bf16.h>

#define NEG 0.2f

// bf16 helpers (manual RNE pack / unpack, branch-free, no NaN inputs here)
__device__ __forceinline__ unsigned short f2bf(float f) {
    unsigned u = __float_as_uint(f);
    u += 0x7fffu + ((u >> 16) & 1u);
    return (unsigned short)(u >> 16);
}
__device__ __forceinline__ unsigned pack2bf(float a, float b) {
    return (unsigned)f2bf(a) | ((unsigned)f2bf(b) << 16);
}
__device__ __forceinline__ float bflo(unsigned u) { return __uint_as_float(u << 16); }
__device__ __forceinline__ float bfhi(unsigned u) { return __uint_as_float(u & 0xffff0000u); }

// ---------------------------------------------------------------------------
// K1: h = x @ proj_w + proj_b  (N x 128, stored bf16) and 4 per-node alpha dots.
// Block 256 = 8 nodes/iter, 32 threads/node, 4 cols (float4) each.
// ---------------------------------------------------------------------------
__global__ __launch_bounds__(256) void proj_kernel(
    const float* __restrict__ x, const float* __restrict__ pw,
    const float* __restrict__ pb,
    const float* __restrict__ ls0, const float* __restrict__ ld0,
    const float* __restrict__ ls1, const float* __restrict__ ld1,
    unsigned* __restrict__ hbf, float* __restrict__ as0, float* __restrict__ ad0,
    float* __restrict__ as1, float* __restrict__ ad1, int N)
{
    __shared__ float4 Ws[128][32];   // 64 KB
    __shared__ float  Xs[8][128];    // 4 KB
    __shared__ float  lin[4][128];   // 2 KB
    __shared__ float  bsh[128];
    int t = threadIdx.x;
    for (int i = t; i < 4096; i += 256) {
        int r = i >> 5, c = i & 31;
        Ws[r][c] = reinterpret_cast<const float4*>(pw)[i];
    }
    for (int i = t; i < 128; i += 256) {
        lin[0][i] = ls0[i]; lin[1][i] = ld0[i];
        lin[2][i] = ls1[i]; lin[3][i] = ld1[i];
        bsh[i] = pb[i];
    }
    int ln = t >> 5, tg = t & 31;
    int head = tg >> 2, dbase = (tg & 3) * 4;
    int ngroups = (N + 7) >> 3;
    for (int g = blockIdx.x; g < ngroups; g += gridDim.x) {
        int n0 = g << 3;
        __syncthreads();
        {
            int i = t;
            int r = i >> 5, c = i & 31; int n = n0 + r;
            float4 v = make_float4(0.f, 0.f, 0.f, 0.f);
            if (n < N) v = reinterpret_cast<const float4*>(x)[(size_t)n * 32 + c];
            reinterpret_cast<float4*>(&Xs[0][0])[i] = v;
        }
        __syncthreads();
        int n = n0 + ln;
        float4 acc = make_float4(0.f, 0.f, 0.f, 0.f);
        #pragma unroll 8
        for (int k = 0; k < 128; ++k) {
            float xv = Xs[ln][k];
            float4 w = Ws[k][tg];
            acc.x = fmaf(xv, w.x, acc.x); acc.y = fmaf(xv, w.y, acc.y);
            acc.z = fmaf(xv, w.z, acc.z); acc.w = fmaf(xv, w.w, acc.w);
        }
        float4 b4 = reinterpret_cast<const float4*>(bsh)[tg];
        acc.x += b4.x; acc.y += b4.y; acc.z += b4.z; acc.w += b4.w;
        if (n < N) {
            uint2 p;
            p.x = pack2bf(acc.x, acc.y);
            p.y = pack2bf(acc.z, acc.w);
            reinterpret_cast<uint2*>(hbf)[(size_t)n * 32 + tg] = p;
        }
        float* outs[4] = {as0, ad0, as1, ad1};
        #pragma unroll
        for (int s = 0; s < 4; ++s) {
            const float* lv = &lin[s][head * 16 + dbase];
            float p = acc.x * lv[0] + acc.y * lv[1] + acc.z * lv[2] + acc.w * lv[3];
            p += __shfl_xor(p, 1);
            p += __shfl_xor(p, 2);
            if ((tg & 3) == 0 && n < N) outs[s][n * 8 + head] = p;
        }
    }
}

// ---------------------------------------------------------------------------
// CSR build: histogram of dst, exclusive scan, fill perm with src ids.
// ---------------------------------------------------------------------------
__global__ __launch_bounds__(256) void hist_kernel(
    const int* __restrict__ ei, int E, int* __restrict__ deg)
{
    int i = blockIdx.x * blockDim.x + threadIdx.x;
    int stride = gridDim.x * blockDim.x;
    for (int e = i; e < E; e += stride) {
        int d = ei[E + e];
        atomicAdd(&deg[d], 1);
    }
}

__global__ __launch_bounds__(256) void scan1_kernel(
    const int* __restrict__ in, int* __restrict__ out, int* __restrict__ bsums, int n)
{
    __shared__ int sh[256];
    int t = threadIdx.x;
    int i = blockIdx.x * 256 + t;
    int v = (i < n) ? in[i] : 0;
    sh[t] = v;
    __syncthreads();
    for (int ofs = 1; ofs < 256; ofs <<= 1) {
        int xv = (t >= ofs) ? sh[t - ofs] : 0;
        __syncthreads();
        sh[t] += xv;
        __syncthreads();
    }
    if (i < n) out[i] = sh[t] - v;          // exclusive
    if (t == 255) bsums[blockIdx.x] = sh[255];
}

__global__ __launch_bounds__(512) void scan2_kernel(int* __restrict__ bs, int nb)
{
    __shared__ int sh[512];
    int t = threadIdx.x;
    int v = (t < nb) ? bs[t] : 0;
    sh[t] = v;
    __syncthreads();
    for (int ofs = 1; ofs < 512; ofs <<= 1) {
        int xv = (t >= ofs) ? sh[t - ofs] : 0;
        __syncthreads();
        sh[t] += xv;
        __syncthreads();
    }
    if (t < nb) bs[t] = sh[t] - v;          // exclusive
}

__global__ __launch_bounds__(256) void scan3_kernel(
    int* __restrict__ out, const int* __restrict__ bs, int n)
{
    int i = blockIdx.x * 256 + threadIdx.x;
    if (i < n) out[i] += bs[blockIdx.x];
}

__global__ __launch_bounds__(256) void fill_kernel(
    const int* __restrict__ ei, int E, const int* __restrict__ off,
    int* __restrict__ cur, int* __restrict__ perm)
{
    int i = blockIdx.x * blockDim.x + threadIdx.x;
    int stride = gridDim.x * blockDim.x;
    for (int e = i; e < E; e += stride) {
        int s = ei[e];
        int d = ei[E + e];
        int p = atomicAdd(&cur[d], 1);
        perm[off[d] + p] = s;
    }
}

// ---------------------------------------------------------------------------
// K3: per-destination aggregation, ONE pass (out = sum(e*h[src]) / sum(e)).
// One 64-lane wave per node; lane owns dims {2*lane, 2*lane+1} (bf16x2 = 4B).
// segment_max skipped: alpha bounded (|alpha|<~3), softmax shift-invariant.
// Unroll-2 with independent accumulators to keep 2 gathers in flight.
// ---------------------------------------------------------------------------
__global__ __launch_bounds__(256) void agg_kernel(
    const int* __restrict__ off, const int* __restrict__ perm,
    const float* __restrict__ asrc, const float* __restrict__ adst,
    const unsigned* __restrict__ hbf, unsigned* __restrict__ outm, int N)
{
    int wid = blockIdx.x * (blockDim.x >> 6) + (threadIdx.x >> 6);
    int lane = threadIdx.x & 63;
    if (wid >= N) return;
    int start = off[wid], end = off[wid + 1];
    int h2 = lane >> 3;   // head owning this lane's dims
    float av = adst[wid * 8 + h2];
    float acc0 = 0.f, acc1 = 0.f, ssum = 0.f;
    float acc0b = 0.f, acc1b = 0.f, ssumb = 0.f;
    int i = start;
    for (; i + 1 < end; i += 2) {
        int s0 = perm[i];
        int s1 = perm[i + 1];
        float al0 = asrc[s0 * 8 + h2] + av;
        float al1 = asrc[s1 * 8 + h2] + av;
        unsigned u0 = hbf[(size_t)s0 * 64 + lane];
        unsigned u1 = hbf[(size_t)s1 * 64 + lane];
        al0 = al0 > 0.f ? al0 : NEG * al0;
        al1 = al1 > 0.f ? al1 : NEG * al1;
        float e0 = __expf(al0);
        float e1 = __expf(al1);
        acc0  = fmaf(bflo(u0), e0, acc0);
        acc1  = fmaf(bfhi(u0), e0, acc1);
        ssum += e0;
        acc0b  = fmaf(bflo(u1), e1, acc0b);
        acc1b  = fmaf(bfhi(u1), e1, acc1b);
        ssumb += e1;
    }
    if (i < end) {
        int s0 = perm[i];
        float al0 = asrc[s0 * 8 + h2] + av;
        unsigned u0 = hbf[(size_t)s0 * 64 + lane];
        al0 = al0 > 0.f ? al0 : NEG * al0;
        float e0 = __expf(al0);
        acc0  = fmaf(bflo(u0), e0, acc0);
        acc1  = fmaf(bfhi(u0), e0, acc1);
        ssum += e0;
    }
    acc0 += acc0b; acc1 += acc1b; ssum += ssumb;
    float inv = 1.f / (ssum + 1e-16f);
    acc0 *= inv; acc1 *= inv;
    acc0 = acc0 > 0.f ? acc0 : 0.f;   // relu
    acc1 = acc1 > 0.f ? acc1 : 0.f;
    outm[(size_t)wid * 64 + lane] = pack2bf(acc0, acc1);
}

// ---------------------------------------------------------------------------
// K4: semantic-attention scores over bf16 out0/out1 (block-local partials).
// ---------------------------------------------------------------------------
__global__ __launch_bounds__(256) void score_kernel(
    const unsigned* __restrict__ o0, const unsigned* __restrict__ o1,
    const float* __restrict__ kw, const float* __restrict__ kb,
    const float* __restrict__ q, float* __restrict__ partials, int N)
{
    __shared__ float4 Ws[128][32];
    __shared__ float  Xs[8][128];
    __shared__ float  kbs[128];
    __shared__ float  qs[128];
    __shared__ float  red[256];
    int t = threadIdx.x;
    for (int i = t; i < 4096; i += 256) {
        int r = i >> 5, c = i & 31;
        Ws[r][c] = reinterpret_cast<const float4*>(kw)[i];
    }
    for (int i = t; i < 128; i += 256) { kbs[i] = kb[i]; qs[i] = q[i]; }
    int ln = t >> 5, tg = t & 31;
    int ngpm = (N + 7) >> 3;
    float bs0 = 0.f, bs1 = 0.f;
    for (int g = blockIdx.x; g < 2 * ngpm; g += gridDim.x) {
        int m = (g >= ngpm);
        const unsigned* om = m ? o1 : o0;
        int n0 = (g - m * ngpm) << 3;
        __syncthreads();
        if (t < 128) {  // 8 rows x 16 uint4 (each uint4 = 8 bf16 dims)
            int r = t >> 4, c = t & 15; int n = n0 + r;
            uint4 v = make_uint4(0u, 0u, 0u, 0u);
            if (n < N) v = reinterpret_cast<const uint4*>(om)[(size_t)n * 16 + c];
            float* xr = &Xs[r][c * 8];
            xr[0] = bflo(v.x); xr[1] = bfhi(v.x);
            xr[2] = bflo(v.y); xr[3] = bfhi(v.y);
            xr[4] = bflo(v.z); xr[5] = bfhi(v.z);
            xr[6] = bflo(v.w); xr[7] = bfhi(v.w);
        }
        __syncthreads();
        int n = n0 + ln;
        float4 acc = reinterpret_cast<const float4*>(kbs)[tg];
        #pragma unroll 8
        for (int k = 0; k < 128; ++k) {
            float xv = Xs[ln][k];
            float4 w = Ws[k][tg];
            acc.x = fmaf(xv, w.x, acc.x); acc.y = fmaf(xv, w.y, acc.y);
            acc.z = fmaf(xv, w.z, acc.z); acc.w = fmaf(xv, w.w, acc.w);
        }
        float4 q4 = reinterpret_cast<const float4*>(qs)[tg];
        float p = q4.x * tanhf(acc.x) + q4.y * tanhf(acc.y)
                + q4.z * tanhf(acc.z) + q4.w * tanhf(acc.w);
        if (n >= N) p = 0.f;
        if (m) bs1 += p; else bs0 += p;
    }
    __syncthreads();
    red[t] = bs0; __syncthreads();
    for (int o = 128; o > 0; o >>= 1) {
        if (t < o) red[t] += red[t + o];
        __syncthreads();
    }
    if (t == 0) partials[blockIdx.x * 2] = red[0];
    __syncthreads();
    red[t] = bs1; __syncthreads();
    for (int o = 128; o > 0; o >>= 1) {
        if (t < o) red[t] += red[t + o];
        __syncthreads();
    }
    if (t == 0) partials[blockIdx.x * 2 + 1] = red[0];
}

__global__ __launch_bounds__(256) void beta_kernel(
    const float* __restrict__ partials, int G, float invN, float* __restrict__ beta)
{
    __shared__ float r0[256], r1[256];
    int t = threadIdx.x;
    float s0 = 0.f, s1 = 0.f;
    for (int i = t; i < G; i += 256) { s0 += partials[i * 2]; s1 += partials[i * 2 + 1]; }
    r0[t] = s0; r1[t] = s1; __syncthreads();
    for (int o = 128; o > 0; o >>= 1) {
        if (t < o) { r0[t] += r0[t + o]; r1[t] += r1[t + o]; }
        __syncthreads();
    }
    if (t == 0) {
        float a = r0[0] * invN, b = r1[0] * invN;
        float mx = fmaxf(a, b);
        float ea = __expf(a - mx), eb = __expf(b - mx);
        float inv = 1.f / (ea + eb);
        beta[0] = ea * inv; beta[1] = eb * inv;
    }
}

// ---------------------------------------------------------------------------
// K6: y = (b0*out0 + b1*out1) @ out_w + out_b   (bf16 inputs, f32 output)
// ---------------------------------------------------------------------------
__global__ __launch_bounds__(256) void final_kernel(
    const unsigned* __restrict__ o0, const unsigned* __restrict__ o1,
    const float* __restrict__ beta, const float* __restrict__ ow,
    const float* __restrict__ ob, float* __restrict__ y, int N)
{
    __shared__ float4 Ws[128][16];   // 32 KB
    __shared__ float  Xs[16][128];   // 8 KB
    __shared__ float  obs[64];
    int t = threadIdx.x;
    for (int i = t; i < 2048; i += 256) {
        int r = i >> 4, c = i & 15;
        Ws[r][c] = reinterpret_cast<const float4*>(ow)[i];
    }
    if (t < 64) obs[t] = ob[t];
    float b0 = beta[0], b1 = beta[1];
    int ln = t >> 4, tg = t & 15;
    int ngroups = (N + 15) >> 4;
    for (int g = blockIdx.x; g < ngroups; g += gridDim.x) {
        int n0 = g << 4;
        __syncthreads();
        {   // 16 rows x 16 uint4 per array: one (o0,o1) uint4-pair per thread
            int r = t >> 4, c = t & 15; int n = n0 + r;
            uint4 va = make_uint4(0u, 0u, 0u, 0u), vb = va;
            if (n < N) {
                va = reinterpret_cast<const uint4*>(o0)[(size_t)n * 16 + c];
                vb = reinterpret_cast<const uint4*>(o1)[(size_t)n * 16 + c];
            }
            float* xr = &Xs[r][c * 8];
            xr[0] = b0 * bflo(va.x) + b1 * bflo(vb.x);
            xr[1] = b0 * bfhi(va.x) + b1 * bfhi(vb.x);
            xr[2] = b0 * bflo(va.y) + b1 * bflo(vb.y);
            xr[3] = b0 * bfhi(va.y) + b1 * bfhi(vb.y);
            xr[4] = b0 * bflo(va.z) + b1 * bflo(vb.z);
            xr[5] = b0 * bfhi(va.z) + b1 * bfhi(vb.z);
            xr[6] = b0 * bflo(va.w) + b1 * bflo(vb.w);
            xr[7] = b0 * bfhi(va.w) + b1 * bfhi(vb.w);
        }
        __syncthreads();
        int n = n0 + ln;
        float4 acc = reinterpret_cast<const float4*>(obs)[tg];
        #pragma unroll 8
        for (int k = 0; k < 128; ++k) {
            float xv = Xs[ln][k];
            float4 w = Ws[k][tg];
            acc.x = fmaf(xv, w.x, acc.x); acc.y = fmaf(xv, w.y, acc.y);
            acc.z = fmaf(xv, w.z, acc.z); acc.w = fmaf(xv, w.w, acc.w);
        }
        if (n < N) reinterpret_cast<float4*>(y)[(size_t)n * 16 + tg] = acc;
    }
}

// ---------------------------------------------------------------------------
extern "C" void kernel_launch(void* const* d_in, const int* in_sizes, int n_in,
                              void* d_out, int out_size, void* d_ws, size_t ws_size,
                              hipStream_t stream)
{
    const float* x   = (const float*)d_in[0];
    const int*   ei0 = (const int*)d_in[1];
    const int*   ei1 = (const int*)d_in[2];
    const float* pw  = (const float*)d_in[3];
    const float* pb  = (const float*)d_in[4];
    const float* ls0 = (const float*)d_in[5];
    const float* ld0 = (const float*)d_in[6];
    const float* ls1 = (const float*)d_in[7];
    const float* ld1 = (const float*)d_in[8];
    const float* kw  = (const float*)d_in[9];
    const float* kb  = (const float*)d_in[10];
    const float* q   = (const float*)d_in[11];
    const float* ow  = (const float*)d_in[12];
    const float* ob  = (const float*)d_in[13];
    int N  = in_sizes[0] / 128;
    int E0 = in_sizes[1] / 2;
    int E1 = in_sizes[2] / 2;

    char* w = (char*)d_ws;
    size_t o = 0;
    auto alloc = [&](size_t bytes) -> void* {
        void* p = w + o;
        o += (bytes + 255) & ~(size_t)255;
        return p;
    };
    unsigned* hbf  = (unsigned*)alloc((size_t)N * 128 * 2);   // bf16 h
    float* as0  = (float*)alloc((size_t)N * 8 * 4);
    float* ad0  = (float*)alloc((size_t)N * 8 * 4);
    float* as1  = (float*)alloc((size_t)N * 8 * 4);
    float* ad1  = (float*)alloc((size_t)N * 8 * 4);
    unsigned* out0 = (unsigned*)alloc((size_t)N * 128 * 2);   // bf16 out
    unsigned* out1 = (unsigned*)alloc((size_t)N * 128 * 2);
    char*  zbase = w + o;                       // contiguous zeroed region
    int* deg0 = (int*)alloc((size_t)(N + 1) * 4);
    int* cur0 = (int*)alloc((size_t)N * 4);
    int* deg1 = (int*)alloc((size_t)(N + 1) * 4);
    int* cur1 = (int*)alloc((size_t)N * 4);
    size_t zbytes = (w + o) - zbase;
    int* off0 = (int*)alloc((size_t)(N + 1) * 4);
    int* off1 = (int*)alloc((size_t)(N + 1) * 4);
    int* bsums = (int*)alloc(1024 * 4);
    int* perm0 = (int*)alloc((size_t)E0 * 4);
    int* perm1 = (int*)alloc((size_t)E1 * 4);
    float* partials = (float*)alloc((size_t)2 * 2048 * 4);
    float* beta = (float*)alloc(256);

    hipMemsetAsync(zbase, 0, zbytes, stream);

    proj_kernel<<<1024, 256, 0, stream>>>(x, pw, pb, ls0, ld0, ls1, ld1,
                                          hbf, as0, ad0, as1, ad1, N);

    hist_kernel<<<2048, 256, 0, stream>>>(ei0, E0, deg0);
    hist_kernel<<<2048, 256, 0, stream>>>(ei1, E1, deg1);

    int n1 = N + 1;
    int nb = (n1 + 255) / 256;
    scan1_kernel<<<nb, 256, 0, stream>>>(deg0, off0, bsums, n1);
    scan2_kernel<<<1, 512, 0, stream>>>(bsums, nb);
    scan3_kernel<<<nb, 256, 0, stream>>>(off0, bsums, n1);
    scan1_kernel<<<nb, 256, 0, stream>>>(deg1, off1, bsums, n1);
    scan2_kernel<<<1, 512, 0, stream>>>(bsums, nb);
    scan3_kernel<<<nb, 256, 0, stream>>>(off1, bsums, n1);

    fill_kernel<<<2048, 256, 0, stream>>>(ei0, E0, off0, cur0, perm0);
    fill_kernel<<<2048, 256, 0, stream>>>(ei1, E1, off1, cur1, perm1);

    int aggBlocks = (N + 3) / 4;
    agg_kernel<<<aggBlocks, 256, 0, stream>>>(off0, perm0, as0, ad0, hbf, out0, N);
    agg_kernel<<<aggBlocks, 256, 0, stream>>>(off1, perm1, as1, ad1, hbf, out1, N);

    const int SG = 1024;
    score_kernel<<<SG, 256, 0, stream>>>(out0, out1, kw, kb, q, partials, N);
    beta_kernel<<<1, 256, 0, stream>>>(partials, SG, 1.0f / (float)N, beta);
    final_kernel<<<1024, 256, 0, stream>>>(out0, out1, beta, ow, ob, (float*)d_out, N);
}

// Round 7
// 654.712 us; speedup vs baseline: 1.6102x; 1.3992x over previous
//
#include <hip/hip_runtime.h>
#include <hip/hip_bf16.h>

#define NEG 0.2f

typedef __attribute__((ext_vector_type(8))) short short8;  // 8 bf16 (4 VGPR)
typedef __attribute__((ext_vector_type(4))) float f32x4;

// bf16 helpers (manual RNE pack / unpack, branch-free, no NaN inputs here)
__device__ __forceinline__ unsigned short f2bf(float f) {
    unsigned u = __float_as_uint(f);
    u += 0x7fffu + ((u >> 16) & 1u);
    return (unsigned short)(u >> 16);
}
__device__ __forceinline__ unsigned pack2bf(float a, float b) {
    return (unsigned)f2bf(a) | ((unsigned)f2bf(b) << 16);
}
__device__ __forceinline__ float bflo(unsigned u) { return __uint_as_float(u << 16); }
__device__ __forceinline__ float bfhi(unsigned u) { return __uint_as_float(u & 0xffff0000u); }

__device__ __forceinline__ short8 asfrag(uint4 v) {
    union { uint4 u; short8 s; } x; x.u = v; return x.s;
}
__device__ __forceinline__ f32x4 mfma_bf16(short8 a, short8 b, f32x4 c) {
    return __builtin_amdgcn_mfma_f32_16x16x32_bf16(a, b, c, 0, 0, 0);
}
__device__ __forceinline__ float tanh_fast(float x) {
    x = fminf(fmaxf(x, -15.f), 15.f);
    float t = __expf(2.f * x);
    return (t - 1.f) / (t + 1.f);
}

// ---------------------------------------------------------------------------
// P0: pre-pack weight matrices into MFMA B-fragment order (once).
// Fragment: lane l supplies B[kt*32+(l>>4)*8+j][nt*16+(l&15)], j=0..7, as
// 8 k-consecutive bf16 in a uint4.  Layout: dst[nt*256 + kt*64 + lane].
// block 0: proj_w [128x128], block 1: k_w [128x128], block 2: out_w [128x64].
// ---------------------------------------------------------------------------
__global__ __launch_bounds__(256) void prep_bfrag(
    const float* __restrict__ pw, const float* __restrict__ kw,
    const float* __restrict__ ow,
    uint4* __restrict__ bfpw, uint4* __restrict__ bfkw, uint4* __restrict__ bfow)
{
    int b = blockIdx.x;
    const float* src = (b == 0) ? pw : (b == 1) ? kw : ow;
    uint4* dst = (b == 0) ? bfpw : (b == 1) ? bfkw : bfow;
    int ncol  = (b == 2) ? 64 : 128;
    int slots = (b == 2) ? 1024 : 2048;
    for (int i = threadIdx.x; i < slots; i += 256) {
        int nt = i >> 8, kt = (i >> 6) & 3, lane = i & 63;
        int row0 = kt * 32 + ((lane >> 4) << 3);
        int col  = nt * 16 + (lane & 15);
        float e[8];
        #pragma unroll
        for (int j = 0; j < 8; ++j) e[j] = src[(row0 + j) * ncol + col];
        uint4 v;
        v.x = pack2bf(e[0], e[1]); v.y = pack2bf(e[2], e[3]);
        v.z = pack2bf(e[4], e[5]); v.w = pack2bf(e[6], e[7]);
        dst[i] = v;
    }
}

// ---------------------------------------------------------------------------
// K1: h = bf16(x) @ bf16(proj_w) + proj_b via MFMA; store h bf16.
// One wave per 16-row tile; 8 col-tiles x 4 k-tiles = 32 MFMA per tile.
// ---------------------------------------------------------------------------
__global__ __launch_bounds__(256) void proj_mfma(
    const float* __restrict__ x, const uint4* __restrict__ bfg,
    const float* __restrict__ pb, unsigned short* __restrict__ hst, int N)
{
    __shared__ uint4 Bf[2048];   // 32 KB
    __shared__ float pbs[128];
    int t = threadIdx.x;
    for (int i = t; i < 2048; i += 256) Bf[i] = bfg[i];
    if (t < 128) pbs[t] = pb[t];
    __syncthreads();
    int wid = t >> 6, l = t & 63, l15 = l & 15, lhi = l >> 4;
    float bv[8];
    #pragma unroll
    for (int nt = 0; nt < 8; ++nt) bv[nt] = pbs[nt * 16 + l15];
    int ntiles = (N + 15) >> 4;
    const float4* X4 = reinterpret_cast<const float4*>(x);
    for (int rt = blockIdx.x * 4 + wid; rt < ntiles; rt += gridDim.x * 4) {
        int row = rt * 16 + l15;
        f32x4 acc[8];
        #pragma unroll
        for (int nt = 0; nt < 8; ++nt) acc[nt] = (f32x4)(0.f);
        #pragma unroll
        for (int kt = 0; kt < 4; ++kt) {
            uint4 af = make_uint4(0u, 0u, 0u, 0u);
            if (row < N) {
                float4 xa = X4[(size_t)row * 32 + kt * 8 + lhi * 2];
                float4 xb = X4[(size_t)row * 32 + kt * 8 + lhi * 2 + 1];
                af.x = pack2bf(xa.x, xa.y); af.y = pack2bf(xa.z, xa.w);
                af.z = pack2bf(xb.x, xb.y); af.w = pack2bf(xb.z, xb.w);
            }
            short8 a = asfrag(af);
            #pragma unroll
            for (int nt = 0; nt < 8; ++nt)
                acc[nt] = mfma_bf16(a, asfrag(Bf[nt * 256 + kt * 64 + l]), acc[nt]);
        }
        #pragma unroll
        for (int r = 0; r < 4; ++r) {
            int orow = rt * 16 + lhi * 4 + r;
            if (orow < N) {
                #pragma unroll
                for (int nt = 0; nt < 8; ++nt)
                    hst[(size_t)orow * 128 + nt * 16 + l15] = f2bf(acc[nt][r] + bv[nt]);
            }
        }
    }
}

// ---------------------------------------------------------------------------
// K2: per-node attention coefficients from bf16 h (memory-bound).
// thread = (node, head): 32B h read, 4 x 16-dot, 4 coalesced f32 writes.
// ---------------------------------------------------------------------------
__global__ __launch_bounds__(256) void alpha_kernel(
    const unsigned* __restrict__ hbf,
    const float* __restrict__ ls0, const float* __restrict__ ld0,
    const float* __restrict__ ls1, const float* __restrict__ ld1,
    float* __restrict__ as0, float* __restrict__ ad0,
    float* __restrict__ as1, float* __restrict__ ad1, int N)
{
    __shared__ float lin[512];
    int t = threadIdx.x;
    for (int i = t; i < 128; i += 256) {
        lin[i] = ls0[i]; lin[128 + i] = ld0[i];
        lin[256 + i] = ls1[i]; lin[384 + i] = ld1[i];
    }
    __syncthreads();
    int idx = blockIdx.x * 256 + t;
    if (idx >= N * 8) return;
    int node = idx >> 3, head = idx & 7;
    const uint4* H = reinterpret_cast<const uint4*>(hbf);
    uint4 va = H[(size_t)node * 16 + head * 2];
    uint4 vb = H[(size_t)node * 16 + head * 2 + 1];
    float h[16];
    h[0] = bflo(va.x); h[1] = bfhi(va.x); h[2] = bflo(va.y); h[3] = bfhi(va.y);
    h[4] = bflo(va.z); h[5] = bfhi(va.z); h[6] = bflo(va.w); h[7] = bfhi(va.w);
    h[8] = bflo(vb.x); h[9] = bfhi(vb.x); h[10] = bflo(vb.y); h[11] = bfhi(vb.y);
    h[12] = bflo(vb.z); h[13] = bfhi(vb.z); h[14] = bflo(vb.w); h[15] = bfhi(vb.w);
    int base = head * 16;
    float d0 = 0.f, d1 = 0.f, d2 = 0.f, d3 = 0.f;
    #pragma unroll
    for (int d = 0; d < 16; ++d) {
        float hv = h[d];
        d0 = fmaf(hv, lin[base + d], d0);
        d1 = fmaf(hv, lin[128 + base + d], d1);
        d2 = fmaf(hv, lin[256 + base + d], d2);
        d3 = fmaf(hv, lin[384 + base + d], d3);
    }
    as0[idx] = d0; ad0[idx] = d1; as1[idx] = d2; ad1[idx] = d3;
}

// ---------------------------------------------------------------------------
// CSR build: histogram of dst, exclusive scan, fill perm with src ids.
// ---------------------------------------------------------------------------
__global__ __launch_bounds__(256) void hist_kernel(
    const int* __restrict__ ei, int E, int* __restrict__ deg)
{
    int i = blockIdx.x * blockDim.x + threadIdx.x;
    int stride = gridDim.x * blockDim.x;
    for (int e = i; e < E; e += stride) {
        int d = ei[E + e];
        atomicAdd(&deg[d], 1);
    }
}

__global__ __launch_bounds__(256) void scan1_kernel(
    const int* __restrict__ in, int* __restrict__ out, int* __restrict__ bsums, int n)
{
    __shared__ int sh[256];
    int t = threadIdx.x;
    int i = blockIdx.x * 256 + t;
    int v = (i < n) ? in[i] : 0;
    sh[t] = v;
    __syncthreads();
    for (int ofs = 1; ofs < 256; ofs <<= 1) {
        int xv = (t >= ofs) ? sh[t - ofs] : 0;
        __syncthreads();
        sh[t] += xv;
        __syncthreads();
    }
    if (i < n) out[i] = sh[t] - v;          // exclusive
    if (t == 255) bsums[blockIdx.x] = sh[255];
}

__global__ __launch_bounds__(512) void scan2_kernel(int* __restrict__ bs, int nb)
{
    __shared__ int sh[512];
    int t = threadIdx.x;
    int v = (t < nb) ? bs[t] : 0;
    sh[t] = v;
    __syncthreads();
    for (int ofs = 1; ofs < 512; ofs <<= 1) {
        int xv = (t >= ofs) ? sh[t - ofs] : 0;
        __syncthreads();
        sh[t] += xv;
        __syncthreads();
    }
    if (t < nb) bs[t] = sh[t] - v;          // exclusive
}

__global__ __launch_bounds__(256) void scan3_kernel(
    int* __restrict__ out, const int* __restrict__ bs, int n)
{
    int i = blockIdx.x * 256 + threadIdx.x;
    if (i < n) out[i] += bs[blockIdx.x];
}

__global__ __launch_bounds__(256) void fill_kernel(
    const int* __restrict__ ei, int E, const int* __restrict__ off,
    int* __restrict__ cur, int* __restrict__ perm)
{
    int i = blockIdx.x * blockDim.x + threadIdx.x;
    int stride = gridDim.x * blockDim.x;
    for (int e = i; e < E; e += stride) {
        int s = ei[e];
        int d = ei[E + e];
        int p = atomicAdd(&cur[d], 1);
        perm[off[d] + p] = s;
    }
}

// ---------------------------------------------------------------------------
// K3: per-destination aggregation, ONE pass (out = sum(e*h[src]) / sum(e)).
// One 64-lane wave per node; lane owns dims {2*lane, 2*lane+1} (bf16x2 = 4B).
// segment_max skipped: alpha bounded, softmax shift-invariant.
// ---------------------------------------------------------------------------
__global__ __launch_bounds__(256) void agg_kernel(
    const int* __restrict__ off, const int* __restrict__ perm,
    const float* __restrict__ asrc, const float* __restrict__ adst,
    const unsigned* __restrict__ hbf, unsigned* __restrict__ outm, int N)
{
    int wid = blockIdx.x * (blockDim.x >> 6) + (threadIdx.x >> 6);
    int lane = threadIdx.x & 63;
    if (wid >= N) return;
    int start = off[wid], end = off[wid + 1];
    int h2 = lane >> 3;   // head owning this lane's dims
    float av = adst[wid * 8 + h2];
    float acc0 = 0.f, acc1 = 0.f, ssum = 0.f;
    float acc0b = 0.f, acc1b = 0.f, ssumb = 0.f;
    int i = start;
    for (; i + 1 < end; i += 2) {
        int s0 = perm[i];
        int s1 = perm[i + 1];
        float al0 = asrc[s0 * 8 + h2] + av;
        float al1 = asrc[s1 * 8 + h2] + av;
        unsigned u0 = hbf[(size_t)s0 * 64 + lane];
        unsigned u1 = hbf[(size_t)s1 * 64 + lane];
        al0 = al0 > 0.f ? al0 : NEG * al0;
        al1 = al1 > 0.f ? al1 : NEG * al1;
        float e0 = __expf(al0);
        float e1 = __expf(al1);
        acc0  = fmaf(bflo(u0), e0, acc0);
        acc1  = fmaf(bfhi(u0), e0, acc1);
        ssum += e0;
        acc0b  = fmaf(bflo(u1), e1, acc0b);
        acc1b  = fmaf(bfhi(u1), e1, acc1b);
        ssumb += e1;
    }
    if (i < end) {
        int s0 = perm[i];
        float al0 = asrc[s0 * 8 + h2] + av;
        unsigned u0 = hbf[(size_t)s0 * 64 + lane];
        al0 = al0 > 0.f ? al0 : NEG * al0;
        float e0 = __expf(al0);
        acc0  = fmaf(bflo(u0), e0, acc0);
        acc1  = fmaf(bfhi(u0), e0, acc1);
        ssum += e0;
    }
    acc0 += acc0b; acc1 += acc1b; ssum += ssumb;
    float inv = 1.f / (ssum + 1e-16f);
    acc0 *= inv; acc1 *= inv;
    acc0 = acc0 > 0.f ? acc0 : 0.f;   // relu
    acc1 = acc1 > 0.f ? acc1 : 0.f;
    outm[(size_t)wid * 64 + lane] = pack2bf(acc0, acc1);
}

// ---------------------------------------------------------------------------
// K4: semantic-attention scores via MFMA over bf16 out0/out1.
// wave tile = 16 rows x 128 cols; epilogue tanh+q-dot, block partials.
// ---------------------------------------------------------------------------
__global__ __launch_bounds__(256) void score_mfma(
    const unsigned* __restrict__ o0, const unsigned* __restrict__ o1,
    const uint4* __restrict__ bfg, const float* __restrict__ kb,
    const float* __restrict__ q, float* __restrict__ partials, int N)
{
    __shared__ uint4 Bf[2048];   // 32 KB (k_w fragments)
    __shared__ float kbs[128], qs[128];
    __shared__ float red[2];
    int t = threadIdx.x;
    for (int i = t; i < 2048; i += 256) Bf[i] = bfg[i];
    if (t < 128) { kbs[t] = kb[t]; qs[t] = q[t]; }
    if (t < 2) red[t] = 0.f;
    __syncthreads();
    int wid = t >> 6, l = t & 63, l15 = l & 15, lhi = l >> 4;
    float qv[8], kbv[8];
    #pragma unroll
    for (int nt = 0; nt < 8; ++nt) {
        qv[nt] = qs[nt * 16 + l15];
        kbv[nt] = kbs[nt * 16 + l15];
    }
    int ntiles = (N + 15) >> 4;
    int ttiles = 2 * ntiles;
    const uint4* A0 = reinterpret_cast<const uint4*>(o0);
    const uint4* A1 = reinterpret_cast<const uint4*>(o1);
    for (int tid = blockIdx.x * 4 + wid; tid < ttiles; tid += gridDim.x * 4) {
        int m = (tid >= ntiles);
        int rt = tid - (m ? ntiles : 0);
        const uint4* A = m ? A1 : A0;
        int row = rt * 16 + l15;
        f32x4 acc[8];
        #pragma unroll
        for (int nt = 0; nt < 8; ++nt) acc[nt] = (f32x4)(0.f);
        #pragma unroll
        for (int kt = 0; kt < 4; ++kt) {
            uint4 av = (row < N) ? A[(size_t)row * 16 + kt * 4 + lhi]
                                 : make_uint4(0u, 0u, 0u, 0u);
            short8 a = asfrag(av);
            #pragma unroll
            for (int nt = 0; nt < 8; ++nt)
                acc[nt] = mfma_bf16(a, asfrag(Bf[nt * 256 + kt * 64 + l]), acc[nt]);
        }
        float partial = 0.f;
        int rbase = rt * 16 + lhi * 4;
        #pragma unroll
        for (int r = 0; r < 4; ++r) {
            if (rbase + r < N) {
                #pragma unroll
                for (int nt = 0; nt < 8; ++nt)
                    partial += qv[nt] * tanh_fast(acc[nt][r] + kbv[nt]);
            }
        }
        partial += __shfl_xor(partial, 1);
        partial += __shfl_xor(partial, 2);
        partial += __shfl_xor(partial, 4);
        partial += __shfl_xor(partial, 8);
        partial += __shfl_xor(partial, 16);
        partial += __shfl_xor(partial, 32);
        if (l == 0) atomicAdd(&red[m], partial);
    }
    __syncthreads();
    if (t < 2) partials[blockIdx.x * 2 + t] = red[t];
}

__global__ __launch_bounds__(256) void beta_kernel(
    const float* __restrict__ partials, int G, float invN, float* __restrict__ beta)
{
    __shared__ float r0[256], r1[256];
    int t = threadIdx.x;
    float s0 = 0.f, s1 = 0.f;
    for (int i = t; i < G; i += 256) { s0 += partials[i * 2]; s1 += partials[i * 2 + 1]; }
    r0[t] = s0; r1[t] = s1; __syncthreads();
    for (int o = 128; o > 0; o >>= 1) {
        if (t < o) { r0[t] += r0[t + o]; r1[t] += r1[t + o]; }
        __syncthreads();
    }
    if (t == 0) {
        float a = r0[0] * invN, b = r1[0] * invN;
        float mx = fmaxf(a, b);
        float ea = __expf(a - mx), eb = __expf(b - mx);
        float inv = 1.f / (ea + eb);
        beta[0] = ea * inv; beta[1] = eb * inv;
    }
}

// ---------------------------------------------------------------------------
// K6: y = (b0*out0 + b1*out1) @ out_w + out_b via MFMA (f32 output).
// ---------------------------------------------------------------------------
__global__ __launch_bounds__(256) void final_mfma(
    const unsigned* __restrict__ o0, const unsigned* __restrict__ o1,
    const uint4* __restrict__ bfg, const float* __restrict__ ob,
    const float* __restrict__ beta, float* __restrict__ y, int N)
{
    __shared__ uint4 Bf[1024];   // 16 KB (out_w fragments)
    __shared__ float obs[64];
    int t = threadIdx.x;
    for (int i = t; i < 1024; i += 256) Bf[i] = bfg[i];
    if (t < 64) obs[t] = ob[t];
    __syncthreads();
    float b0 = beta[0], b1 = beta[1];
    int wid = t >> 6, l = t & 63, l15 = l & 15, lhi = l >> 4;
    float obv[4];
    #pragma unroll
    for (int nt = 0; nt < 4; ++nt) obv[nt] = obs[nt * 16 + l15];
    int ntiles = (N + 15) >> 4;
    const uint4* A0 = reinterpret_cast<const uint4*>(o0);
    const uint4* A1 = reinterpret_cast<const uint4*>(o1);
    for (int rt = blockIdx.x * 4 + wid; rt < ntiles; rt += gridDim.x * 4) {
        int row = rt * 16 + l15;
        f32x4 acc[4];
        #pragma unroll
        for (int nt = 0; nt < 4; ++nt) acc[nt] = (f32x4)(0.f);
        #pragma unroll
        for (int kt = 0; kt < 4; ++kt) {
            uint4 af = make_uint4(0u, 0u, 0u, 0u);
            if (row < N) {
                uint4 a0 = A0[(size_t)row * 16 + kt * 4 + lhi];
                uint4 a1 = A1[(size_t)row * 16 + kt * 4 + lhi];
                af.x = pack2bf(b0 * bflo(a0.x) + b1 * bflo(a1.x),
                               b0 * bfhi(a0.x) + b1 * bfhi(a1.x));
                af.y = pack2bf(b0 * bflo(a0.y) + b1 * bflo(a1.y),
                               b0 * bfhi(a0.y) + b1 * bfhi(a1.y));
                af.z = pack2bf(b0 * bflo(a0.z) + b1 * bflo(a1.z),
                               b0 * bfhi(a0.z) + b1 * bfhi(a1.z));
                af.w = pack2bf(b0 * bflo(a0.w) + b1 * bflo(a1.w),
                               b0 * bfhi(a0.w) + b1 * bfhi(a1.w));
            }
            short8 a = asfrag(af);
            #pragma unroll
            for (int nt = 0; nt < 4; ++nt)
                acc[nt] = mfma_bf16(a, asfrag(Bf[nt * 256 + kt * 64 + l]), acc[nt]);
        }
        #pragma unroll
        for (int r = 0; r < 4; ++r) {
            int orow = rt * 16 + lhi * 4 + r;
            if (orow < N) {
                #pragma unroll
                for (int nt = 0; nt < 4; ++nt)
                    y[(size_t)orow * 64 + nt * 16 + l15] = acc[nt][r] + obv[nt];
            }
        }
    }
}

// ---------------------------------------------------------------------------
extern "C" void kernel_launch(void* const* d_in, const int* in_sizes, int n_in,
                              void* d_out, int out_size, void* d_ws, size_t ws_size,
                              hipStream_t stream)
{
    const float* x   = (const float*)d_in[0];
    const int*   ei0 = (const int*)d_in[1];
    const int*   ei1 = (const int*)d_in[2];
    const float* pw  = (const float*)d_in[3];
    const float* pb  = (const float*)d_in[4];
    const float* ls0 = (const float*)d_in[5];
    const float* ld0 = (const float*)d_in[6];
    const float* ls1 = (const float*)d_in[7];
    const float* ld1 = (const float*)d_in[8];
    const float* kw  = (const float*)d_in[9];
    const float* kb  = (const float*)d_in[10];
    const float* q   = (const float*)d_in[11];
    const float* ow  = (const float*)d_in[12];
    const float* ob  = (const float*)d_in[13];
    int N  = in_sizes[0] / 128;
    int E0 = in_sizes[1] / 2;
    int E1 = in_sizes[2] / 2;

    char* w = (char*)d_ws;
    size_t o = 0;
    auto alloc = [&](size_t bytes) -> void* {
        void* p = w + o;
        o += (bytes + 255) & ~(size_t)255;
        return p;
    };
    unsigned* hbf  = (unsigned*)alloc((size_t)N * 128 * 2);   // bf16 h
    float* as0  = (float*)alloc((size_t)N * 8 * 4);
    float* ad0  = (float*)alloc((size_t)N * 8 * 4);
    float* as1  = (float*)alloc((size_t)N * 8 * 4);
    float* ad1  = (float*)alloc((size_t)N * 8 * 4);
    unsigned* out0 = (unsigned*)alloc((size_t)N * 128 * 2);   // bf16 out
    unsigned* out1 = (unsigned*)alloc((size_t)N * 128 * 2);
    char*  zbase = w + o;                       // contiguous zeroed region
    int* deg0 = (int*)alloc((size_t)(N + 1) * 4);
    int* cur0 = (int*)alloc((size_t)N * 4);
    int* deg1 = (int*)alloc((size_t)(N + 1) * 4);
    int* cur1 = (int*)alloc((size_t)N * 4);
    size_t zbytes = (w + o) - zbase;
    int* off0 = (int*)alloc((size_t)(N + 1) * 4);
    int* off1 = (int*)alloc((size_t)(N + 1) * 4);
    int* bsums = (int*)alloc(1024 * 4);
    int* perm0 = (int*)alloc((size_t)E0 * 4);
    int* perm1 = (int*)alloc((size_t)E1 * 4);
    float* partials = (float*)alloc((size_t)2 * 2048 * 4);
    float* beta = (float*)alloc(256);
    uint4* bfpw = (uint4*)alloc(2048 * 16);
    uint4* bfkw = (uint4*)alloc(2048 * 16);
    uint4* bfow = (uint4*)alloc(1024 * 16);

    hipMemsetAsync(zbase, 0, zbytes, stream);

    prep_bfrag<<<3, 256, 0, stream>>>(pw, kw, ow, bfpw, bfkw, bfow);

    proj_mfma<<<512, 256, 0, stream>>>(x, bfpw, pb, (unsigned short*)hbf, N);

    int ablocks = (N * 8 + 255) / 256;
    alpha_kernel<<<ablocks, 256, 0, stream>>>(hbf, ls0, ld0, ls1, ld1,
                                              as0, ad0, as1, ad1, N);

    hist_kernel<<<2048, 256, 0, stream>>>(ei0, E0, deg0);
    hist_kernel<<<2048, 256, 0, stream>>>(ei1, E1, deg1);

    int n1 = N + 1;
    int nb = (n1 + 255) / 256;
    scan1_kernel<<<nb, 256, 0, stream>>>(deg0, off0, bsums, n1);
    scan2_kernel<<<1, 512, 0, stream>>>(bsums, nb);
    scan3_kernel<<<nb, 256, 0, stream>>>(off0, bsums, n1);
    scan1_kernel<<<nb, 256, 0, stream>>>(deg1, off1, bsums, n1);
    scan2_kernel<<<1, 512, 0, stream>>>(bsums, nb);
    scan3_kernel<<<nb, 256, 0, stream>>>(off1, bsums, n1);

    fill_kernel<<<2048, 256, 0, stream>>>(ei0, E0, off0, cur0, perm0);
    fill_kernel<<<2048, 256, 0, stream>>>(ei1, E1, off1, cur1, perm1);

    int aggBlocks = (N + 3) / 4;
    agg_kernel<<<aggBlocks, 256, 0, stream>>>(off0, perm0, as0, ad0, hbf, out0, N);
    agg_kernel<<<aggBlocks, 256, 0, stream>>>(off1, perm1, as1, ad1, hbf, out1, N);

    const int SG = 512;
    score_mfma<<<SG, 256, 0, stream>>>(out0, out1, bfkw, kb, q, partials, N);
    beta_kernel<<<1, 256, 0, stream>>>(partials, SG, 1.0f / (float)N, beta);
    final_mfma<<<512, 256, 0, stream>>>(out0, out1, bfow, ob, beta, (float*)d_out, N);
}

// Round 8
// 557.433 us; speedup vs baseline: 1.8912x; 1.1745x over previous
//
#include <hip/hip_runtime.h>
#include <hip/hip_bf16.h>

#define NEG 0.2f

typedef __attribute__((ext_vector_type(8))) short short8;  // 8 bf16 (4 VGPR)
typedef __attribute__((ext_vector_type(4))) float f32x4;

// bf16 helpers (manual RNE pack / unpack, branch-free, no NaN inputs here)
__device__ __forceinline__ unsigned short f2bf(float f) {
    unsigned u = __float_as_uint(f);
    u += 0x7fffu + ((u >> 16) & 1u);
    return (unsigned short)(u >> 16);
}
__device__ __forceinline__ unsigned pack2bf(float a, float b) {
    return (unsigned)f2bf(a) | ((unsigned)f2bf(b) << 16);
}
__device__ __forceinline__ float bflo(unsigned u) { return __uint_as_float(u << 16); }
__device__ __forceinline__ float bfhi(unsigned u) { return __uint_as_float(u & 0xffff0000u); }

__device__ __forceinline__ short8 asfrag(uint4 v) {
    union { uint4 u; short8 s; } x; x.u = v; return x.s;
}
__device__ __forceinline__ f32x4 mfma_bf16(short8 a, short8 b, f32x4 c) {
    return __builtin_amdgcn_mfma_f32_16x16x32_bf16(a, b, c, 0, 0, 0);
}
__device__ __forceinline__ float tanh_fast(float x) {
    x = fminf(fmaxf(x, -15.f), 15.f);
    float t = __expf(2.f * x);
    return (t - 1.f) / (t + 1.f);
}

// ---------------------------------------------------------------------------
// P0: pre-pack weight matrices into MFMA B-fragment order (once).
// block 0: proj_w [128x128], block 1: k_w [128x128], block 2: out_w [128x64].
// ---------------------------------------------------------------------------
__global__ __launch_bounds__(256) void prep_bfrag(
    const float* __restrict__ pw, const float* __restrict__ kw,
    const float* __restrict__ ow,
    uint4* __restrict__ bfpw, uint4* __restrict__ bfkw, uint4* __restrict__ bfow)
{
    int b = blockIdx.x;
    const float* src = (b == 0) ? pw : (b == 1) ? kw : ow;
    uint4* dst = (b == 0) ? bfpw : (b == 1) ? bfkw : bfow;
    int ncol  = (b == 2) ? 64 : 128;
    int slots = (b == 2) ? 1024 : 2048;
    for (int i = threadIdx.x; i < slots; i += 256) {
        int nt = i >> 8, kt = (i >> 6) & 3, lane = i & 63;
        int row0 = kt * 32 + ((lane >> 4) << 3);
        int col  = nt * 16 + (lane & 15);
        float e[8];
        #pragma unroll
        for (int j = 0; j < 8; ++j) e[j] = src[(row0 + j) * ncol + col];
        uint4 v;
        v.x = pack2bf(e[0], e[1]); v.y = pack2bf(e[2], e[3]);
        v.z = pack2bf(e[4], e[5]); v.w = pack2bf(e[6], e[7]);
        dst[i] = v;
    }
}

// ---------------------------------------------------------------------------
// K1: h = bf16(x) @ bf16(proj_w) + proj_b via MFMA; store h bf16.
// ---------------------------------------------------------------------------
__global__ __launch_bounds__(256) void proj_mfma(
    const float* __restrict__ x, const uint4* __restrict__ bfg,
    const float* __restrict__ pb, unsigned short* __restrict__ hst, int N)
{
    __shared__ uint4 Bf[2048];   // 32 KB
    __shared__ float pbs[128];
    int t = threadIdx.x;
    for (int i = t; i < 2048; i += 256) Bf[i] = bfg[i];
    if (t < 128) pbs[t] = pb[t];
    __syncthreads();
    int wid = t >> 6, l = t & 63, l15 = l & 15, lhi = l >> 4;
    float bv[8];
    #pragma unroll
    for (int nt = 0; nt < 8; ++nt) bv[nt] = pbs[nt * 16 + l15];
    int ntiles = (N + 15) >> 4;
    const float4* X4 = reinterpret_cast<const float4*>(x);
    for (int rt = blockIdx.x * 4 + wid; rt < ntiles; rt += gridDim.x * 4) {
        int row = rt * 16 + l15;
        f32x4 acc[8];
        #pragma unroll
        for (int nt = 0; nt < 8; ++nt) acc[nt] = (f32x4)(0.f);
        #pragma unroll
        for (int kt = 0; kt < 4; ++kt) {
            uint4 af = make_uint4(0u, 0u, 0u, 0u);
            if (row < N) {
                float4 xa = X4[(size_t)row * 32 + kt * 8 + lhi * 2];
                float4 xb = X4[(size_t)row * 32 + kt * 8 + lhi * 2 + 1];
                af.x = pack2bf(xa.x, xa.y); af.y = pack2bf(xa.z, xa.w);
                af.z = pack2bf(xb.x, xb.y); af.w = pack2bf(xb.z, xb.w);
            }
            short8 a = asfrag(af);
            #pragma unroll
            for (int nt = 0; nt < 8; ++nt)
                acc[nt] = mfma_bf16(a, asfrag(Bf[nt * 256 + kt * 64 + l]), acc[nt]);
        }
        #pragma unroll
        for (int r = 0; r < 4; ++r) {
            int orow = rt * 16 + lhi * 4 + r;
            if (orow < N) {
                #pragma unroll
                for (int nt = 0; nt < 8; ++nt)
                    hst[(size_t)orow * 128 + nt * 16 + l15] = f2bf(acc[nt][r] + bv[nt]);
            }
        }
    }
}

// ---------------------------------------------------------------------------
// K2: per-node attention coefficients from bf16 h (memory-bound).
// ---------------------------------------------------------------------------
__global__ __launch_bounds__(256) void alpha_kernel(
    const unsigned* __restrict__ hbf,
    const float* __restrict__ ls0, const float* __restrict__ ld0,
    const float* __restrict__ ls1, const float* __restrict__ ld1,
    float* __restrict__ as0, float* __restrict__ ad0,
    float* __restrict__ as1, float* __restrict__ ad1, int N)
{
    __shared__ float lin[512];
    int t = threadIdx.x;
    for (int i = t; i < 128; i += 256) {
        lin[i] = ls0[i]; lin[128 + i] = ld0[i];
        lin[256 + i] = ls1[i]; lin[384 + i] = ld1[i];
    }
    __syncthreads();
    int idx = blockIdx.x * 256 + t;
    if (idx >= N * 8) return;
    int node = idx >> 3, head = idx & 7;
    const uint4* H = reinterpret_cast<const uint4*>(hbf);
    uint4 va = H[(size_t)node * 16 + head * 2];
    uint4 vb = H[(size_t)node * 16 + head * 2 + 1];
    float h[16];
    h[0] = bflo(va.x); h[1] = bfhi(va.x); h[2] = bflo(va.y); h[3] = bfhi(va.y);
    h[4] = bflo(va.z); h[5] = bfhi(va.z); h[6] = bflo(va.w); h[7] = bfhi(va.w);
    h[8] = bflo(vb.x); h[9] = bfhi(vb.x); h[10] = bflo(vb.y); h[11] = bfhi(vb.y);
    h[12] = bflo(vb.z); h[13] = bfhi(vb.z); h[14] = bflo(vb.w); h[15] = bfhi(vb.w);
    int base = head * 16;
    float d0 = 0.f, d1 = 0.f, d2 = 0.f, d3 = 0.f;
    #pragma unroll
    for (int d = 0; d < 16; ++d) {
        float hv = h[d];
        d0 = fmaf(hv, lin[base + d], d0);
        d1 = fmaf(hv, lin[128 + base + d], d1);
        d2 = fmaf(hv, lin[256 + base + d], d2);
        d3 = fmaf(hv, lin[384 + base + d], d3);
    }
    as0[idx] = d0; ad0[idx] = d1; as1[idx] = d2; ad1[idx] = d3;
}

// ---------------------------------------------------------------------------
// CSR build, XCD-region-aware + fused over both metapaths.
// Block-group (mp, xg=blockIdx&7) handles only dst region xg -> perm/deg
// lines stay in ONE XCD's L2 (write amp ~1).  8x dst re-read is L3-served.
// ---------------------------------------------------------------------------
__global__ __launch_bounds__(256) void hist_fused(
    const int* __restrict__ ei0, int E0, int* __restrict__ deg0,
    const int* __restrict__ ei1, int E1, int* __restrict__ deg1, int rsize)
{
    int xg = blockIdx.x & 7;
    int mp = (blockIdx.x >> 3) & 1;
    int sub = blockIdx.x >> 4;            // [0,256)
    const int* ei = mp ? ei1 : ei0;
    int E = mp ? E1 : E0;
    int* deg = mp ? deg1 : deg0;
    const int stride = 256 * 256;
    for (int e = sub * 256 + threadIdx.x; e < E; e += stride) {
        int d = ei[E + e];
        if (d / rsize == xg) atomicAdd(&deg[d], 1);
    }
}

__global__ __launch_bounds__(256) void fill_fused(
    const int* __restrict__ ei0, int E0, const int* __restrict__ off0,
    int* __restrict__ cur0, int* __restrict__ perm0,
    const int* __restrict__ ei1, int E1, const int* __restrict__ off1,
    int* __restrict__ cur1, int* __restrict__ perm1, int rsize)
{
    int xg = blockIdx.x & 7;
    int mp = (blockIdx.x >> 3) & 1;
    int sub = blockIdx.x >> 4;            // [0,256)
    const int* ei = mp ? ei1 : ei0;
    int E = mp ? E1 : E0;
    const int* off = mp ? off1 : off0;
    int* cur = mp ? cur1 : cur0;
    int* perm = mp ? perm1 : perm0;
    const int stride = 256 * 256;
    for (int e = sub * 256 + threadIdx.x; e < E; e += stride) {
        int d = ei[E + e];
        if (d / rsize == xg) {
            int s = ei[e];
            int p = atomicAdd(&cur[d], 1);
            perm[off[d] + p] = s;
        }
    }
}

// ---------------------------------------------------------------------------
// Scans (fused over both metapaths).
// ---------------------------------------------------------------------------
__global__ __launch_bounds__(256) void scan1_fused(
    const int* __restrict__ in0, int* __restrict__ out0,
    const int* __restrict__ in1, int* __restrict__ out1,
    int* __restrict__ bsums, int n, int nb)
{
    __shared__ int sh[256];
    int mp = (blockIdx.x >= (unsigned)nb);
    int blk = blockIdx.x - (mp ? nb : 0);
    const int* in = mp ? in1 : in0;
    int* out = mp ? out1 : out0;
    int t = threadIdx.x;
    int i = blk * 256 + t;
    int v = (i < n) ? in[i] : 0;
    sh[t] = v;
    __syncthreads();
    for (int ofs = 1; ofs < 256; ofs <<= 1) {
        int xv = (t >= ofs) ? sh[t - ofs] : 0;
        __syncthreads();
        sh[t] += xv;
        __syncthreads();
    }
    if (i < n) out[i] = sh[t] - v;          // exclusive
    if (t == 255) bsums[mp * 512 + blk] = sh[255];
}

__global__ __launch_bounds__(512) void scan2_fused(int* __restrict__ bs, int nb)
{
    __shared__ int sh[512];
    int t = threadIdx.x;
    int* b = bs + blockIdx.x * 512;
    int v = (t < nb) ? b[t] : 0;
    sh[t] = v;
    __syncthreads();
    for (int ofs = 1; ofs < 512; ofs <<= 1) {
        int xv = (t >= ofs) ? sh[t - ofs] : 0;
        __syncthreads();
        sh[t] += xv;
        __syncthreads();
    }
    if (t < nb) b[t] = sh[t] - v;          // exclusive
}

__global__ __launch_bounds__(256) void scan3_fused(
    int* __restrict__ out0, int* __restrict__ out1,
    const int* __restrict__ bs, int n, int nb)
{
    int mp = (blockIdx.x >= (unsigned)nb);
    int blk = blockIdx.x - (mp ? nb : 0);
    int* out = mp ? out1 : out0;
    int i = blk * 256 + threadIdx.x;
    if (i < n) out[i] += bs[mp * 512 + blk];
}

// ---------------------------------------------------------------------------
// K3: per-destination aggregation (fused mp0+mp1), ONE pass.
// One 64-lane wave per (mp, node); lane owns dims {2*lane, 2*lane+1}.
// ---------------------------------------------------------------------------
__global__ __launch_bounds__(256) void agg_fused(
    const int* __restrict__ off0, const int* __restrict__ perm0,
    const float* __restrict__ as0, const float* __restrict__ ad0,
    const int* __restrict__ off1, const int* __restrict__ perm1,
    const float* __restrict__ as1, const float* __restrict__ ad1,
    const unsigned* __restrict__ hbf,
    unsigned* __restrict__ o0, unsigned* __restrict__ o1, int N)
{
    int mp = blockIdx.x & 1;
    int wid = (blockIdx.x >> 1) * 4 + (threadIdx.x >> 6);
    int lane = threadIdx.x & 63;
    if (wid >= N) return;
    const int* off = mp ? off1 : off0;
    const int* perm = mp ? perm1 : perm0;
    const float* asrc = mp ? as1 : as0;
    const float* adst = mp ? ad1 : ad0;
    unsigned* outm = mp ? o1 : o0;
    int start = off[wid], end = off[wid + 1];
    int h2 = lane >> 3;
    float av = adst[wid * 8 + h2];
    float acc0 = 0.f, acc1 = 0.f, ssum = 0.f;
    float acc0b = 0.f, acc1b = 0.f, ssumb = 0.f;
    int i = start;
    for (; i + 1 < end; i += 2) {
        int s0 = perm[i];
        int s1 = perm[i + 1];
        float al0 = asrc[s0 * 8 + h2] + av;
        float al1 = asrc[s1 * 8 + h2] + av;
        unsigned u0 = hbf[(size_t)s0 * 64 + lane];
        unsigned u1 = hbf[(size_t)s1 * 64 + lane];
        al0 = al0 > 0.f ? al0 : NEG * al0;
        al1 = al1 > 0.f ? al1 : NEG * al1;
        float e0 = __expf(al0);
        float e1 = __expf(al1);
        acc0  = fmaf(bflo(u0), e0, acc0);
        acc1  = fmaf(bfhi(u0), e0, acc1);
        ssum += e0;
        acc0b  = fmaf(bflo(u1), e1, acc0b);
        acc1b  = fmaf(bfhi(u1), e1, acc1b);
        ssumb += e1;
    }
    if (i < end) {
        int s0 = perm[i];
        float al0 = asrc[s0 * 8 + h2] + av;
        unsigned u0 = hbf[(size_t)s0 * 64 + lane];
        al0 = al0 > 0.f ? al0 : NEG * al0;
        float e0 = __expf(al0);
        acc0  = fmaf(bflo(u0), e0, acc0);
        acc1  = fmaf(bfhi(u0), e0, acc1);
        ssum += e0;
    }
    acc0 += acc0b; acc1 += acc1b; ssum += ssumb;
    float inv = 1.f / (ssum + 1e-16f);
    acc0 *= inv; acc1 *= inv;
    acc0 = acc0 > 0.f ? acc0 : 0.f;   // relu
    acc1 = acc1 > 0.f ? acc1 : 0.f;
    outm[(size_t)wid * 64 + lane] = pack2bf(acc0, acc1);
}

// ---------------------------------------------------------------------------
// K4: semantic-attention scores via MFMA over bf16 out0/out1.
// ---------------------------------------------------------------------------
__global__ __launch_bounds__(256) void score_mfma(
    const unsigned* __restrict__ o0, const unsigned* __restrict__ o1,
    const uint4* __restrict__ bfg, const float* __restrict__ kb,
    const float* __restrict__ q, float* __restrict__ partials, int N)
{
    __shared__ uint4 Bf[2048];   // 32 KB (k_w fragments)
    __shared__ float kbs[128], qs[128];
    __shared__ float red[2];
    int t = threadIdx.x;
    for (int i = t; i < 2048; i += 256) Bf[i] = bfg[i];
    if (t < 128) { kbs[t] = kb[t]; qs[t] = q[t]; }
    if (t < 2) red[t] = 0.f;
    __syncthreads();
    int wid = t >> 6, l = t & 63, l15 = l & 15, lhi = l >> 4;
    float qv[8], kbv[8];
    #pragma unroll
    for (int nt = 0; nt < 8; ++nt) {
        qv[nt] = qs[nt * 16 + l15];
        kbv[nt] = kbs[nt * 16 + l15];
    }
    int ntiles = (N + 15) >> 4;
    int ttiles = 2 * ntiles;
    const uint4* A0 = reinterpret_cast<const uint4*>(o0);
    const uint4* A1 = reinterpret_cast<const uint4*>(o1);
    for (int tid = blockIdx.x * 4 + wid; tid < ttiles; tid += gridDim.x * 4) {
        int m = (tid >= ntiles);
        int rt = tid - (m ? ntiles : 0);
        const uint4* A = m ? A1 : A0;
        int row = rt * 16 + l15;
        f32x4 acc[8];
        #pragma unroll
        for (int nt = 0; nt < 8; ++nt) acc[nt] = (f32x4)(0.f);
        #pragma unroll
        for (int kt = 0; kt < 4; ++kt) {
            uint4 av = (row < N) ? A[(size_t)row * 16 + kt * 4 + lhi]
                                 : make_uint4(0u, 0u, 0u, 0u);
            short8 a = asfrag(av);
            #pragma unroll
            for (int nt = 0; nt < 8; ++nt)
                acc[nt] = mfma_bf16(a, asfrag(Bf[nt * 256 + kt * 64 + l]), acc[nt]);
        }
        float partial = 0.f;
        int rbase = rt * 16 + lhi * 4;
        #pragma unroll
        for (int r = 0; r < 4; ++r) {
            if (rbase + r < N) {
                #pragma unroll
                for (int nt = 0; nt < 8; ++nt)
                    partial += qv[nt] * tanh_fast(acc[nt][r] + kbv[nt]);
            }
        }
        partial += __shfl_xor(partial, 1);
        partial += __shfl_xor(partial, 2);
        partial += __shfl_xor(partial, 4);
        partial += __shfl_xor(partial, 8);
        partial += __shfl_xor(partial, 16);
        partial += __shfl_xor(partial, 32);
        if (l == 0) atomicAdd(&red[m], partial);
    }
    __syncthreads();
    if (t < 2) partials[blockIdx.x * 2 + t] = red[t];
}

__global__ __launch_bounds__(256) void beta_kernel(
    const float* __restrict__ partials, int G, float invN, float* __restrict__ beta)
{
    __shared__ float r0[256], r1[256];
    int t = threadIdx.x;
    float s0 = 0.f, s1 = 0.f;
    for (int i = t; i < G; i += 256) { s0 += partials[i * 2]; s1 += partials[i * 2 + 1]; }
    r0[t] = s0; r1[t] = s1; __syncthreads();
    for (int o = 128; o > 0; o >>= 1) {
        if (t < o) { r0[t] += r0[t + o]; r1[t] += r1[t + o]; }
        __syncthreads();
    }
    if (t == 0) {
        float a = r0[0] * invN, b = r1[0] * invN;
        float mx = fmaxf(a, b);
        float ea = __expf(a - mx), eb = __expf(b - mx);
        float inv = 1.f / (ea + eb);
        beta[0] = ea * inv; beta[1] = eb * inv;
    }
}

// ---------------------------------------------------------------------------
// K6: y = (b0*out0 + b1*out1) @ out_w + out_b via MFMA (f32 output).
// ---------------------------------------------------------------------------
__global__ __launch_bounds__(256) void final_mfma(
    const unsigned* __restrict__ o0, const unsigned* __restrict__ o1,
    const uint4* __restrict__ bfg, const float* __restrict__ ob,
    const float* __restrict__ beta, float* __restrict__ y, int N)
{
    __shared__ uint4 Bf[1024];   // 16 KB (out_w fragments)
    __shared__ float obs[64];
    int t = threadIdx.x;
    for (int i = t; i < 1024; i += 256) Bf[i] = bfg[i];
    if (t < 64) obs[t] = ob[t];
    __syncthreads();
    float b0 = beta[0], b1 = beta[1];
    int wid = t >> 6, l = t & 63, l15 = l & 15, lhi = l >> 4;
    float obv[4];
    #pragma unroll
    for (int nt = 0; nt < 4; ++nt) obv[nt] = obs[nt * 16 + l15];
    int ntiles = (N + 15) >> 4;
    const uint4* A0 = reinterpret_cast<const uint4*>(o0);
    const uint4* A1 = reinterpret_cast<const uint4*>(o1);
    for (int rt = blockIdx.x * 4 + wid; rt < ntiles; rt += gridDim.x * 4) {
        int row = rt * 16 + l15;
        f32x4 acc[4];
        #pragma unroll
        for (int nt = 0; nt < 4; ++nt) acc[nt] = (f32x4)(0.f);
        #pragma unroll
        for (int kt = 0; kt < 4; ++kt) {
            uint4 af = make_uint4(0u, 0u, 0u, 0u);
            if (row < N) {
                uint4 a0 = A0[(size_t)row * 16 + kt * 4 + lhi];
                uint4 a1 = A1[(size_t)row * 16 + kt * 4 + lhi];
                af.x = pack2bf(b0 * bflo(a0.x) + b1 * bflo(a1.x),
                               b0 * bfhi(a0.x) + b1 * bfhi(a1.x));
                af.y = pack2bf(b0 * bflo(a0.y) + b1 * bflo(a1.y),
                               b0 * bfhi(a0.y) + b1 * bfhi(a1.y));
                af.z = pack2bf(b0 * bflo(a0.z) + b1 * bflo(a1.z),
                               b0 * bfhi(a0.z) + b1 * bfhi(a1.z));
                af.w = pack2bf(b0 * bflo(a0.w) + b1 * bflo(a1.w),
                               b0 * bfhi(a0.w) + b1 * bfhi(a1.w));
            }
            short8 a = asfrag(af);
            #pragma unroll
            for (int nt = 0; nt < 4; ++nt)
                acc[nt] = mfma_bf16(a, asfrag(Bf[nt * 256 + kt * 64 + l]), acc[nt]);
        }
        #pragma unroll
        for (int r = 0; r < 4; ++r) {
            int orow = rt * 16 + lhi * 4 + r;
            if (orow < N) {
                #pragma unroll
                for (int nt = 0; nt < 4; ++nt)
                    y[(size_t)orow * 64 + nt * 16 + l15] = acc[nt][r] + obv[nt];
            }
        }
    }
}

// ---------------------------------------------------------------------------
extern "C" void kernel_launch(void* const* d_in, const int* in_sizes, int n_in,
                              void* d_out, int out_size, void* d_ws, size_t ws_size,
                              hipStream_t stream)
{
    const float* x   = (const float*)d_in[0];
    const int*   ei0 = (const int*)d_in[1];
    const int*   ei1 = (const int*)d_in[2];
    const float* pw  = (const float*)d_in[3];
    const float* pb  = (const float*)d_in[4];
    const float* ls0 = (const float*)d_in[5];
    const float* ld0 = (const float*)d_in[6];
    const float* ls1 = (const float*)d_in[7];
    const float* ld1 = (const float*)d_in[8];
    const float* kw  = (const float*)d_in[9];
    const float* kb  = (const float*)d_in[10];
    const float* q   = (const float*)d_in[11];
    const float* ow  = (const float*)d_in[12];
    const float* ob  = (const float*)d_in[13];
    int N  = in_sizes[0] / 128;
    int E0 = in_sizes[1] / 2;
    int E1 = in_sizes[2] / 2;

    char* w = (char*)d_ws;
    size_t o = 0;
    auto alloc = [&](size_t bytes) -> void* {
        void* p = w + o;
        o += (bytes + 255) & ~(size_t)255;
        return p;
    };
    unsigned* hbf  = (unsigned*)alloc((size_t)N * 128 * 2);   // bf16 h
    float* as0  = (float*)alloc((size_t)N * 8 * 4);
    float* ad0  = (float*)alloc((size_t)N * 8 * 4);
    float* as1  = (float*)alloc((size_t)N * 8 * 4);
    float* ad1  = (float*)alloc((size_t)N * 8 * 4);
    unsigned* out0 = (unsigned*)alloc((size_t)N * 128 * 2);   // bf16 out
    unsigned* out1 = (unsigned*)alloc((size_t)N * 128 * 2);
    char*  zbase = w + o;                       // contiguous zeroed region
    int* deg0 = (int*)alloc((size_t)(N + 1) * 4);
    int* cur0 = (int*)alloc((size_t)N * 4);
    int* deg1 = (int*)alloc((size_t)(N + 1) * 4);
    int* cur1 = (int*)alloc((size_t)N * 4);
    size_t zbytes = (w + o) - zbase;
    int* off0 = (int*)alloc((size_t)(N + 1) * 4);
    int* off1 = (int*)alloc((size_t)(N + 1) * 4);
    int* bsums = (int*)alloc(1024 * 4);
    int* perm0 = (int*)alloc((size_t)E0 * 4);
    int* perm1 = (int*)alloc((size_t)E1 * 4);
    float* partials = (float*)alloc((size_t)2 * 2048 * 4);
    float* beta = (float*)alloc(256);
    uint4* bfpw = (uint4*)alloc(2048 * 16);
    uint4* bfkw = (uint4*)alloc(2048 * 16);
    uint4* bfow = (uint4*)alloc(1024 * 16);

    int rsize = (N + 7) / 8;   // dst-region size for XCD ownership

    hipMemsetAsync(zbase, 0, zbytes, stream);

    prep_bfrag<<<3, 256, 0, stream>>>(pw, kw, ow, bfpw, bfkw, bfow);

    proj_mfma<<<512, 256, 0, stream>>>(x, bfpw, pb, (unsigned short*)hbf, N);

    int ablocks = (N * 8 + 255) / 256;
    alpha_kernel<<<ablocks, 256, 0, stream>>>(hbf, ls0, ld0, ls1, ld1,
                                              as0, ad0, as1, ad1, N);

    hist_fused<<<4096, 256, 0, stream>>>(ei0, E0, deg0, ei1, E1, deg1, rsize);

    int n1 = N + 1;
    int nb = (n1 + 255) / 256;   // must be <= 512
    scan1_fused<<<2 * nb, 256, 0, stream>>>(deg0, off0, deg1, off1, bsums, n1, nb);
    scan2_fused<<<2, 512, 0, stream>>>(bsums, nb);
    scan3_fused<<<2 * nb, 256, 0, stream>>>(off0, off1, bsums, n1, nb);

    fill_fused<<<4096, 256, 0, stream>>>(ei0, E0, off0, cur0, perm0,
                                         ei1, E1, off1, cur1, perm1, rsize);

    int aggBlocks = 2 * ((N + 3) / 4);
    agg_fused<<<aggBlocks, 256, 0, stream>>>(off0, perm0, as0, ad0,
                                             off1, perm1, as1, ad1,
                                             hbf, out0, out1, N);

    const int SG = 512;
    score_mfma<<<SG, 256, 0, stream>>>(out0, out1, bfkw, kb, q, partials, N);
    beta_kernel<<<1, 256, 0, stream>>>(partials, SG, 1.0f / (float)N, beta);
    final_mfma<<<512, 256, 0, stream>>>(out0, out1, bfow, ob, beta, (float*)d_out, N);
}

// Round 9
// 530.025 us; speedup vs baseline: 1.9890x; 1.0517x over previous
//
#include <hip/hip_runtime.h>
#include <hip/hip_bf16.h>

#define NEG 0.2f

typedef __attribute__((ext_vector_type(8))) short short8;  // 8 bf16 (4 VGPR)
typedef __attribute__((ext_vector_type(4))) float f32x4;

// bf16 helpers (manual RNE pack / unpack, branch-free, no NaN inputs here)
__device__ __forceinline__ unsigned short f2bf(float f) {
    unsigned u = __float_as_uint(f);
    u += 0x7fffu + ((u >> 16) & 1u);
    return (unsigned short)(u >> 16);
}
__device__ __forceinline__ unsigned pack2bf(float a, float b) {
    return (unsigned)f2bf(a) | ((unsigned)f2bf(b) << 16);
}
__device__ __forceinline__ float bflo(unsigned u) { return __uint_as_float(u << 16); }
__device__ __forceinline__ float bfhi(unsigned u) { return __uint_as_float(u & 0xffff0000u); }

__device__ __forceinline__ short8 asfrag(uint4 v) {
    union { uint4 u; short8 s; } x; x.u = v; return x.s;
}
__device__ __forceinline__ f32x4 mfma_bf16(short8 a, short8 b, f32x4 c) {
    return __builtin_amdgcn_mfma_f32_16x16x32_bf16(a, b, c, 0, 0, 0);
}
__device__ __forceinline__ float tanh_fast(float x) {
    x = fminf(fmaxf(x, -15.f), 15.f);
    float t = __expf(2.f * x);
    return (t - 1.f) / (t + 1.f);
}

// ---------------------------------------------------------------------------
// P0: pre-pack weight matrices into MFMA B-fragment order (once).
// block 0: proj_w [128x128], block 1: k_w [128x128], block 2: out_w [128x64].
// ---------------------------------------------------------------------------
__global__ __launch_bounds__(256) void prep_bfrag(
    const float* __restrict__ pw, const float* __restrict__ kw,
    const float* __restrict__ ow,
    uint4* __restrict__ bfpw, uint4* __restrict__ bfkw, uint4* __restrict__ bfow)
{
    int b = blockIdx.x;
    const float* src = (b == 0) ? pw : (b == 1) ? kw : ow;
    uint4* dst = (b == 0) ? bfpw : (b == 1) ? bfkw : bfow;
    int ncol  = (b == 2) ? 64 : 128;
    int slots = (b == 2) ? 1024 : 2048;
    for (int i = threadIdx.x; i < slots; i += 256) {
        int nt = i >> 8, kt = (i >> 6) & 3, lane = i & 63;
        int row0 = kt * 32 + ((lane >> 4) << 3);
        int col  = nt * 16 + (lane & 15);
        float e[8];
        #pragma unroll
        for (int j = 0; j < 8; ++j) e[j] = src[(row0 + j) * ncol + col];
        uint4 v;
        v.x = pack2bf(e[0], e[1]); v.y = pack2bf(e[2], e[3]);
        v.z = pack2bf(e[4], e[5]); v.w = pack2bf(e[6], e[7]);
        dst[i] = v;
    }
}

// ---------------------------------------------------------------------------
// K1: h = bf16(x) @ bf16(proj_w) + proj_b via MFMA; store h bf16.
// ---------------------------------------------------------------------------
__global__ __launch_bounds__(256) void proj_mfma(
    const float* __restrict__ x, const uint4* __restrict__ bfg,
    const float* __restrict__ pb, unsigned short* __restrict__ hst, int N)
{
    __shared__ uint4 Bf[2048];   // 32 KB
    __shared__ float pbs[128];
    int t = threadIdx.x;
    for (int i = t; i < 2048; i += 256) Bf[i] = bfg[i];
    if (t < 128) pbs[t] = pb[t];
    __syncthreads();
    int wid = t >> 6, l = t & 63, l15 = l & 15, lhi = l >> 4;
    float bv[8];
    #pragma unroll
    for (int nt = 0; nt < 8; ++nt) bv[nt] = pbs[nt * 16 + l15];
    int ntiles = (N + 15) >> 4;
    const float4* X4 = reinterpret_cast<const float4*>(x);
    for (int rt = blockIdx.x * 4 + wid; rt < ntiles; rt += gridDim.x * 4) {
        int row = rt * 16 + l15;
        f32x4 acc[8];
        #pragma unroll
        for (int nt = 0; nt < 8; ++nt) acc[nt] = (f32x4)(0.f);
        #pragma unroll
        for (int kt = 0; kt < 4; ++kt) {
            uint4 af = make_uint4(0u, 0u, 0u, 0u);
            if (row < N) {
                float4 xa = X4[(size_t)row * 32 + kt * 8 + lhi * 2];
                float4 xb = X4[(size_t)row * 32 + kt * 8 + lhi * 2 + 1];
                af.x = pack2bf(xa.x, xa.y); af.y = pack2bf(xa.z, xa.w);
                af.z = pack2bf(xb.x, xb.y); af.w = pack2bf(xb.z, xb.w);
            }
            short8 a = asfrag(af);
            #pragma unroll
            for (int nt = 0; nt < 8; ++nt)
                acc[nt] = mfma_bf16(a, asfrag(Bf[nt * 256 + kt * 64 + l]), acc[nt]);
        }
        #pragma unroll
        for (int r = 0; r < 4; ++r) {
            int orow = rt * 16 + lhi * 4 + r;
            if (orow < N) {
                #pragma unroll
                for (int nt = 0; nt < 8; ++nt)
                    hst[(size_t)orow * 128 + nt * 16 + l15] = f2bf(acc[nt][r] + bv[nt]);
            }
        }
    }
}

// ---------------------------------------------------------------------------
// K2: per-node attention coefficients from bf16 h (memory-bound).
// ---------------------------------------------------------------------------
__global__ __launch_bounds__(256) void alpha_kernel(
    const unsigned* __restrict__ hbf,
    const float* __restrict__ ls0, const float* __restrict__ ld0,
    const float* __restrict__ ls1, const float* __restrict__ ld1,
    float* __restrict__ as0, float* __restrict__ ad0,
    float* __restrict__ as1, float* __restrict__ ad1, int N)
{
    __shared__ float lin[512];
    int t = threadIdx.x;
    for (int i = t; i < 128; i += 256) {
        lin[i] = ls0[i]; lin[128 + i] = ld0[i];
        lin[256 + i] = ls1[i]; lin[384 + i] = ld1[i];
    }
    __syncthreads();
    int idx = blockIdx.x * 256 + t;
    if (idx >= N * 8) return;
    int node = idx >> 3, head = idx & 7;
    const uint4* H = reinterpret_cast<const uint4*>(hbf);
    uint4 va = H[(size_t)node * 16 + head * 2];
    uint4 vb = H[(size_t)node * 16 + head * 2 + 1];
    float h[16];
    h[0] = bflo(va.x); h[1] = bfhi(va.x); h[2] = bflo(va.y); h[3] = bfhi(va.y);
    h[4] = bflo(va.z); h[5] = bfhi(va.z); h[6] = bflo(va.w); h[7] = bfhi(va.w);
    h[8] = bflo(vb.x); h[9] = bfhi(vb.x); h[10] = bflo(vb.y); h[11] = bfhi(vb.y);
    h[12] = bflo(vb.z); h[13] = bfhi(vb.z); h[14] = bflo(vb.w); h[15] = bfhi(vb.w);
    int base = head * 16;
    float d0 = 0.f, d1 = 0.f, d2 = 0.f, d3 = 0.f;
    #pragma unroll
    for (int d = 0; d < 16; ++d) {
        float hv = h[d];
        d0 = fmaf(hv, lin[base + d], d0);
        d1 = fmaf(hv, lin[128 + base + d], d1);
        d2 = fmaf(hv, lin[256 + base + d], d2);
        d3 = fmaf(hv, lin[384 + base + d], d3);
    }
    as0[idx] = d0; ad0[idx] = d1; as1[idx] = d2; ad1[idx] = d3;
}

// ---------------------------------------------------------------------------
// CSR build, XCD-region-aware + fused over both metapaths.
// ---------------------------------------------------------------------------
__global__ __launch_bounds__(256) void hist_fused(
    const int* __restrict__ ei0, int E0, int* __restrict__ deg0,
    const int* __restrict__ ei1, int E1, int* __restrict__ deg1, int rsize)
{
    int xg = blockIdx.x & 7;
    int mp = (blockIdx.x >> 3) & 1;
    int sub = blockIdx.x >> 4;            // [0,256)
    const int* ei = mp ? ei1 : ei0;
    int E = mp ? E1 : E0;
    int* deg = mp ? deg1 : deg0;
    const int stride = 256 * 256;
    for (int e = sub * 256 + threadIdx.x; e < E; e += stride) {
        int d = ei[E + e];
        if (d / rsize == xg) atomicAdd(&deg[d], 1);
    }
}

__global__ __launch_bounds__(256) void fill_fused(
    const int* __restrict__ ei0, int E0, const int* __restrict__ off0,
    int* __restrict__ cur0, int* __restrict__ perm0,
    const int* __restrict__ ei1, int E1, const int* __restrict__ off1,
    int* __restrict__ cur1, int* __restrict__ perm1, int rsize)
{
    int xg = blockIdx.x & 7;
    int mp = (blockIdx.x >> 3) & 1;
    int sub = blockIdx.x >> 4;            // [0,256)
    const int* ei = mp ? ei1 : ei0;
    int E = mp ? E1 : E0;
    const int* off = mp ? off1 : off0;
    int* cur = mp ? cur1 : cur0;
    int* perm = mp ? perm1 : perm0;
    const int stride = 256 * 256;
    for (int e = sub * 256 + threadIdx.x; e < E; e += stride) {
        int d = ei[E + e];
        if (d / rsize == xg) {
            int s = ei[e];
            int p = atomicAdd(&cur[d], 1);
            perm[off[d] + p] = s;
        }
    }
}

// ---------------------------------------------------------------------------
// Scans (fused over both metapaths).
// ---------------------------------------------------------------------------
__global__ __launch_bounds__(256) void scan1_fused(
    const int* __restrict__ in0, int* __restrict__ out0,
    const int* __restrict__ in1, int* __restrict__ out1,
    int* __restrict__ bsums, int n, int nb)
{
    __shared__ int sh[256];
    int mp = (blockIdx.x >= (unsigned)nb);
    int blk = blockIdx.x - (mp ? nb : 0);
    const int* in = mp ? in1 : in0;
    int* out = mp ? out1 : out0;
    int t = threadIdx.x;
    int i = blk * 256 + t;
    int v = (i < n) ? in[i] : 0;
    sh[t] = v;
    __syncthreads();
    for (int ofs = 1; ofs < 256; ofs <<= 1) {
        int xv = (t >= ofs) ? sh[t - ofs] : 0;
        __syncthreads();
        sh[t] += xv;
        __syncthreads();
    }
    if (i < n) out[i] = sh[t] - v;          // exclusive
    if (t == 255) bsums[mp * 512 + blk] = sh[255];
}

__global__ __launch_bounds__(512) void scan2_fused(int* __restrict__ bs, int nb)
{
    __shared__ int sh[512];
    int t = threadIdx.x;
    int* b = bs + blockIdx.x * 512;
    int v = (t < nb) ? b[t] : 0;
    sh[t] = v;
    __syncthreads();
    for (int ofs = 1; ofs < 512; ofs <<= 1) {
        int xv = (t >= ofs) ? sh[t - ofs] : 0;
        __syncthreads();
        sh[t] += xv;
        __syncthreads();
    }
    if (t < nb) b[t] = sh[t] - v;          // exclusive
}

__global__ __launch_bounds__(256) void scan3_fused(
    int* __restrict__ out0, int* __restrict__ out1,
    const int* __restrict__ bs, int n, int nb)
{
    int mp = (blockIdx.x >= (unsigned)nb);
    int blk = blockIdx.x - (mp ? nb : 0);
    int* out = mp ? out1 : out0;
    int i = blk * 256 + threadIdx.x;
    if (i < n) out[i] += bs[mp * 512 + blk];
}

// ---------------------------------------------------------------------------
// K3: per-destination aggregation (fused mp0+mp1), ONE pass, 8-wide MLP.
// One 64-lane wave per (mp, node); lane owns dims {2*lane, 2*lane+1}.
// Batch of 8 edges: 8 perm loads -> 16 gathers in flight -> masked compute.
// Tail: index clamped to 'start' (safe addr), weight forced to 0.
// ---------------------------------------------------------------------------
__global__ __launch_bounds__(256) void agg_fused(
    const int* __restrict__ off0, const int* __restrict__ perm0,
    const float* __restrict__ as0, const float* __restrict__ ad0,
    const int* __restrict__ off1, const int* __restrict__ perm1,
    const float* __restrict__ as1, const float* __restrict__ ad1,
    const unsigned* __restrict__ hbf,
    unsigned* __restrict__ o0, unsigned* __restrict__ o1, int N)
{
    int mp = blockIdx.x & 1;
    int wid = (blockIdx.x >> 1) * 4 + (threadIdx.x >> 6);
    int lane = threadIdx.x & 63;
    if (wid >= N) return;
    const int* off = mp ? off1 : off0;
    const int* perm = mp ? perm1 : perm0;
    const float* asrc = mp ? as1 : as0;
    const float* adst = mp ? ad1 : ad0;
    unsigned* outm = mp ? o1 : o0;
    int start = off[wid], end = off[wid + 1];
    int h2 = lane >> 3;
    float av = adst[wid * 8 + h2];
    float a0[4] = {0.f, 0.f, 0.f, 0.f};
    float a1[4] = {0.f, 0.f, 0.f, 0.f};
    float ss[4] = {0.f, 0.f, 0.f, 0.f};
    for (int i = start; i < end; i += 8) {
        int s[8];
        #pragma unroll
        for (int k = 0; k < 8; ++k) {
            int idx = i + k;
            s[k] = perm[idx < end ? idx : start];
        }
        float al[8]; unsigned u[8];
        #pragma unroll
        for (int k = 0; k < 8; ++k) {
            al[k] = asrc[s[k] * 8 + h2];
            u[k]  = hbf[(size_t)s[k] * 64 + lane];
        }
        #pragma unroll
        for (int k = 0; k < 8; ++k) {
            float a = al[k] + av;
            a = a > 0.f ? a : NEG * a;
            float e = (i + k < end) ? __expf(a) : 0.f;
            int q = k & 3;
            a0[q] = fmaf(bflo(u[k]), e, a0[q]);
            a1[q] = fmaf(bfhi(u[k]), e, a1[q]);
            ss[q] += e;
        }
    }
    float acc0 = (a0[0] + a0[1]) + (a0[2] + a0[3]);
    float acc1 = (a1[0] + a1[1]) + (a1[2] + a1[3]);
    float ssum = (ss[0] + ss[1]) + (ss[2] + ss[3]);
    float inv = 1.f / (ssum + 1e-16f);
    acc0 *= inv; acc1 *= inv;
    acc0 = acc0 > 0.f ? acc0 : 0.f;   // relu
    acc1 = acc1 > 0.f ? acc1 : 0.f;
    outm[(size_t)wid * 64 + lane] = pack2bf(acc0, acc1);
}

// ---------------------------------------------------------------------------
// K4: semantic-attention scores via MFMA over bf16 out0/out1.
// ---------------------------------------------------------------------------
__global__ __launch_bounds__(256) void score_mfma(
    const unsigned* __restrict__ o0, const unsigned* __restrict__ o1,
    const uint4* __restrict__ bfg, const float* __restrict__ kb,
    const float* __restrict__ q, float* __restrict__ partials, int N)
{
    __shared__ uint4 Bf[2048];   // 32 KB (k_w fragments)
    __shared__ float kbs[128], qs[128];
    __shared__ float red[2];
    int t = threadIdx.x;
    for (int i = t; i < 2048; i += 256) Bf[i] = bfg[i];
    if (t < 128) { kbs[t] = kb[t]; qs[t] = q[t]; }
    if (t < 2) red[t] = 0.f;
    __syncthreads();
    int wid = t >> 6, l = t & 63, l15 = l & 15, lhi = l >> 4;
    float qv[8], kbv[8];
    #pragma unroll
    for (int nt = 0; nt < 8; ++nt) {
        qv[nt] = qs[nt * 16 + l15];
        kbv[nt] = kbs[nt * 16 + l15];
    }
    int ntiles = (N + 15) >> 4;
    int ttiles = 2 * ntiles;
    const uint4* A0 = reinterpret_cast<const uint4*>(o0);
    const uint4* A1 = reinterpret_cast<const uint4*>(o1);
    for (int tid = blockIdx.x * 4 + wid; tid < ttiles; tid += gridDim.x * 4) {
        int m = (tid >= ntiles);
        int rt = tid - (m ? ntiles : 0);
        const uint4* A = m ? A1 : A0;
        int row = rt * 16 + l15;
        f32x4 acc[8];
        #pragma unroll
        for (int nt = 0; nt < 8; ++nt) acc[nt] = (f32x4)(0.f);
        #pragma unroll
        for (int kt = 0; kt < 4; ++kt) {
            uint4 av = (row < N) ? A[(size_t)row * 16 + kt * 4 + lhi]
                                 : make_uint4(0u, 0u, 0u, 0u);
            short8 a = asfrag(av);
            #pragma unroll
            for (int nt = 0; nt < 8; ++nt)
                acc[nt] = mfma_bf16(a, asfrag(Bf[nt * 256 + kt * 64 + l]), acc[nt]);
        }
        float partial = 0.f;
        int rbase = rt * 16 + lhi * 4;
        #pragma unroll
        for (int r = 0; r < 4; ++r) {
            if (rbase + r < N) {
                #pragma unroll
                for (int nt = 0; nt < 8; ++nt)
                    partial += qv[nt] * tanh_fast(acc[nt][r] + kbv[nt]);
            }
        }
        partial += __shfl_xor(partial, 1);
        partial += __shfl_xor(partial, 2);
        partial += __shfl_xor(partial, 4);
        partial += __shfl_xor(partial, 8);
        partial += __shfl_xor(partial, 16);
        partial += __shfl_xor(partial, 32);
        if (l == 0) atomicAdd(&red[m], partial);
    }
    __syncthreads();
    if (t < 2) partials[blockIdx.x * 2 + t] = red[t];
}

__global__ __launch_bounds__(256) void beta_kernel(
    const float* __restrict__ partials, int G, float invN, float* __restrict__ beta)
{
    __shared__ float r0[256], r1[256];
    int t = threadIdx.x;
    float s0 = 0.f, s1 = 0.f;
    for (int i = t; i < G; i += 256) { s0 += partials[i * 2]; s1 += partials[i * 2 + 1]; }
    r0[t] = s0; r1[t] = s1; __syncthreads();
    for (int o = 128; o > 0; o >>= 1) {
        if (t < o) { r0[t] += r0[t + o]; r1[t] += r1[t + o]; }
        __syncthreads();
    }
    if (t == 0) {
        float a = r0[0] * invN, b = r1[0] * invN;
        float mx = fmaxf(a, b);
        float ea = __expf(a - mx), eb = __expf(b - mx);
        float inv = 1.f / (ea + eb);
        beta[0] = ea * inv; beta[1] = eb * inv;
    }
}

// ---------------------------------------------------------------------------
// K6: y = (b0*out0 + b1*out1) @ out_w + out_b via MFMA (f32 output).
// ---------------------------------------------------------------------------
__global__ __launch_bounds__(256) void final_mfma(
    const unsigned* __restrict__ o0, const unsigned* __restrict__ o1,
    const uint4* __restrict__ bfg, const float* __restrict__ ob,
    const float* __restrict__ beta, float* __restrict__ y, int N)
{
    __shared__ uint4 Bf[1024];   // 16 KB (out_w fragments)
    __shared__ float obs[64];
    int t = threadIdx.x;
    for (int i = t; i < 1024; i += 256) Bf[i] = bfg[i];
    if (t < 64) obs[t] = ob[t];
    __syncthreads();
    float b0 = beta[0], b1 = beta[1];
    int wid = t >> 6, l = t & 63, l15 = l & 15, lhi = l >> 4;
    float obv[4];
    #pragma unroll
    for (int nt = 0; nt < 4; ++nt) obv[nt] = obs[nt * 16 + l15];
    int ntiles = (N + 15) >> 4;
    const uint4* A0 = reinterpret_cast<const uint4*>(o0);
    const uint4* A1 = reinterpret_cast<const uint4*>(o1);
    for (int rt = blockIdx.x * 4 + wid; rt < ntiles; rt += gridDim.x * 4) {
        int row = rt * 16 + l15;
        f32x4 acc[4];
        #pragma unroll
        for (int nt = 0; nt < 4; ++nt) acc[nt] = (f32x4)(0.f);
        #pragma unroll
        for (int kt = 0; kt < 4; ++kt) {
            uint4 af = make_uint4(0u, 0u, 0u, 0u);
            if (row < N) {
                uint4 a0 = A0[(size_t)row * 16 + kt * 4 + lhi];
                uint4 a1 = A1[(size_t)row * 16 + kt * 4 + lhi];
                af.x = pack2bf(b0 * bflo(a0.x) + b1 * bflo(a1.x),
                               b0 * bfhi(a0.x) + b1 * bfhi(a1.x));
                af.y = pack2bf(b0 * bflo(a0.y) + b1 * bflo(a1.y),
                               b0 * bfhi(a0.y) + b1 * bfhi(a1.y));
                af.z = pack2bf(b0 * bflo(a0.z) + b1 * bflo(a1.z),
                               b0 * bfhi(a0.z) + b1 * bfhi(a1.z));
                af.w = pack2bf(b0 * bflo(a0.w) + b1 * bflo(a1.w),
                               b0 * bfhi(a0.w) + b1 * bfhi(a1.w));
            }
            short8 a = asfrag(af);
            #pragma unroll
            for (int nt = 0; nt < 4; ++nt)
                acc[nt] = mfma_bf16(a, asfrag(Bf[nt * 256 + kt * 64 + l]), acc[nt]);
        }
        #pragma unroll
        for (int r = 0; r < 4; ++r) {
            int orow = rt * 16 + lhi * 4 + r;
            if (orow < N) {
                #pragma unroll
                for (int nt = 0; nt < 4; ++nt)
                    y[(size_t)orow * 64 + nt * 16 + l15] = acc[nt][r] + obv[nt];
            }
        }
    }
}

// ---------------------------------------------------------------------------
extern "C" void kernel_launch(void* const* d_in, const int* in_sizes, int n_in,
                              void* d_out, int out_size, void* d_ws, size_t ws_size,
                              hipStream_t stream)
{
    const float* x   = (const float*)d_in[0];
    const int*   ei0 = (const int*)d_in[1];
    const int*   ei1 = (const int*)d_in[2];
    const float* pw  = (const float*)d_in[3];
    const float* pb  = (const float*)d_in[4];
    const float* ls0 = (const float*)d_in[5];
    const float* ld0 = (const float*)d_in[6];
    const float* ls1 = (const float*)d_in[7];
    const float* ld1 = (const float*)d_in[8];
    const float* kw  = (const float*)d_in[9];
    const float* kb  = (const float*)d_in[10];
    const float* q   = (const float*)d_in[11];
    const float* ow  = (const float*)d_in[12];
    const float* ob  = (const float*)d_in[13];
    int N  = in_sizes[0] / 128;
    int E0 = in_sizes[1] / 2;
    int E1 = in_sizes[2] / 2;

    char* w = (char*)d_ws;
    size_t o = 0;
    auto alloc = [&](size_t bytes) -> void* {
        void* p = w + o;
        o += (bytes + 255) & ~(size_t)255;
        return p;
    };
    unsigned* hbf  = (unsigned*)alloc((size_t)N * 128 * 2);   // bf16 h
    float* as0  = (float*)alloc((size_t)N * 8 * 4);
    float* ad0  = (float*)alloc((size_t)N * 8 * 4);
    float* as1  = (float*)alloc((size_t)N * 8 * 4);
    float* ad1  = (float*)alloc((size_t)N * 8 * 4);
    unsigned* out0 = (unsigned*)alloc((size_t)N * 128 * 2);   // bf16 out
    unsigned* out1 = (unsigned*)alloc((size_t)N * 128 * 2);
    char*  zbase = w + o;                       // contiguous zeroed region
    int* deg0 = (int*)alloc((size_t)(N + 1) * 4);
    int* cur0 = (int*)alloc((size_t)N * 4);
    int* deg1 = (int*)alloc((size_t)(N + 1) * 4);
    int* cur1 = (int*)alloc((size_t)N * 4);
    size_t zbytes = (w + o) - zbase;
    int* off0 = (int*)alloc((size_t)(N + 1) * 4);
    int* off1 = (int*)alloc((size_t)(N + 1) * 4);
    int* bsums = (int*)alloc(1024 * 4);
    int* perm0 = (int*)alloc((size_t)E0 * 4);
    int* perm1 = (int*)alloc((size_t)E1 * 4);
    float* partials = (float*)alloc((size_t)2 * 2048 * 4);
    float* beta = (float*)alloc(256);
    uint4* bfpw = (uint4*)alloc(2048 * 16);
    uint4* bfkw = (uint4*)alloc(2048 * 16);
    uint4* bfow = (uint4*)alloc(1024 * 16);

    int rsize = (N + 7) / 8;   // dst-region size for XCD ownership

    hipMemsetAsync(zbase, 0, zbytes, stream);

    prep_bfrag<<<3, 256, 0, stream>>>(pw, kw, ow, bfpw, bfkw, bfow);

    proj_mfma<<<512, 256, 0, stream>>>(x, bfpw, pb, (unsigned short*)hbf, N);

    int ablocks = (N * 8 + 255) / 256;
    alpha_kernel<<<ablocks, 256, 0, stream>>>(hbf, ls0, ld0, ls1, ld1,
                                              as0, ad0, as1, ad1, N);

    hist_fused<<<4096, 256, 0, stream>>>(ei0, E0, deg0, ei1, E1, deg1, rsize);

    int n1 = N + 1;
    int nb = (n1 + 255) / 256;   // must be <= 512
    scan1_fused<<<2 * nb, 256, 0, stream>>>(deg0, off0, deg1, off1, bsums, n1, nb);
    scan2_fused<<<2, 512, 0, stream>>>(bsums, nb);
    scan3_fused<<<2 * nb, 256, 0, stream>>>(off0, off1, bsums, n1, nb);

    fill_fused<<<4096, 256, 0, stream>>>(ei0, E0, off0, cur0, perm0,
                                         ei1, E1, off1, cur1, perm1, rsize);

    int aggBlocks = 2 * ((N + 3) / 4);
    agg_fused<<<aggBlocks, 256, 0, stream>>>(off0, perm0, as0, ad0,
                                             off1, perm1, as1, ad1,
                                             hbf, out0, out1, N);

    const int SG = 512;
    score_mfma<<<SG, 256, 0, stream>>>(out0, out1, bfkw, kb, q, partials, N);
    beta_kernel<<<1, 256, 0, stream>>>(partials, SG, 1.0f / (float)N, beta);
    final_mfma<<<512, 256, 0, stream>>>(out0, out1, bfow, ob, beta, (float*)d_out, N);
}

// Round 10
// 508.928 us; speedup vs baseline: 2.0715x; 1.0415x over previous
//
#include <hip/hip_runtime.h>
#include <hip/hip_bf16.h>

#define NEG 0.2f

typedef __attribute__((ext_vector_type(8))) short short8;  // 8 bf16 (4 VGPR)
typedef __attribute__((ext_vector_type(4))) float f32x4;

// bf16 helpers (manual RNE pack / unpack, branch-free, no NaN inputs here)
__device__ __forceinline__ unsigned short f2bf(float f) {
    unsigned u = __float_as_uint(f);
    u += 0x7fffu + ((u >> 16) & 1u);
    return (unsigned short)(u >> 16);
}
__device__ __forceinline__ unsigned pack2bf(float a, float b) {
    return (unsigned)f2bf(a) | ((unsigned)f2bf(b) << 16);
}
__device__ __forceinline__ float bflo(unsigned u) { return __uint_as_float(u << 16); }
__device__ __forceinline__ float bfhi(unsigned u) { return __uint_as_float(u & 0xffff0000u); }

__device__ __forceinline__ short8 asfrag(uint4 v) {
    union { uint4 u; short8 s; } x; x.u = v; return x.s;
}
__device__ __forceinline__ f32x4 mfma_bf16(short8 a, short8 b, f32x4 c) {
    return __builtin_amdgcn_mfma_f32_16x16x32_bf16(a, b, c, 0, 0, 0);
}
__device__ __forceinline__ float tanh_fast(float x) {
    x = fminf(fmaxf(x, -15.f), 15.f);
    float t = __expf(2.f * x);
    return (t - 1.f) / (t + 1.f);
}

// ---------------------------------------------------------------------------
// P0: pre-pack weight matrices into MFMA B-fragment order (once).
// block 0: proj_w [128x128], block 1: k_w [128x128], block 2: out_w [128x64].
// ---------------------------------------------------------------------------
__global__ __launch_bounds__(256) void prep_bfrag(
    const float* __restrict__ pw, const float* __restrict__ kw,
    const float* __restrict__ ow,
    uint4* __restrict__ bfpw, uint4* __restrict__ bfkw, uint4* __restrict__ bfow)
{
    int b = blockIdx.x;
    const float* src = (b == 0) ? pw : (b == 1) ? kw : ow;
    uint4* dst = (b == 0) ? bfpw : (b == 1) ? bfkw : bfow;
    int ncol  = (b == 2) ? 64 : 128;
    int slots = (b == 2) ? 1024 : 2048;
    for (int i = threadIdx.x; i < slots; i += 256) {
        int nt = i >> 8, kt = (i >> 6) & 3, lane = i & 63;
        int row0 = kt * 32 + ((lane >> 4) << 3);
        int col  = nt * 16 + (lane & 15);
        float e[8];
        #pragma unroll
        for (int j = 0; j < 8; ++j) e[j] = src[(row0 + j) * ncol + col];
        uint4 v;
        v.x = pack2bf(e[0], e[1]); v.y = pack2bf(e[2], e[3]);
        v.z = pack2bf(e[4], e[5]); v.w = pack2bf(e[6], e[7]);
        dst[i] = v;
    }
}

// ---------------------------------------------------------------------------
// K1: h = bf16(x) @ bf16(proj_w) + proj_b via MFMA; store h bf16.
// ---------------------------------------------------------------------------
__global__ __launch_bounds__(256) void proj_mfma(
    const float* __restrict__ x, const uint4* __restrict__ bfg,
    const float* __restrict__ pb, unsigned short* __restrict__ hst, int N)
{
    __shared__ uint4 Bf[2048];   // 32 KB
    __shared__ float pbs[128];
    int t = threadIdx.x;
    for (int i = t; i < 2048; i += 256) Bf[i] = bfg[i];
    if (t < 128) pbs[t] = pb[t];
    __syncthreads();
    int wid = t >> 6, l = t & 63, l15 = l & 15, lhi = l >> 4;
    float bv[8];
    #pragma unroll
    for (int nt = 0; nt < 8; ++nt) bv[nt] = pbs[nt * 16 + l15];
    int ntiles = (N + 15) >> 4;
    const float4* X4 = reinterpret_cast<const float4*>(x);
    for (int rt = blockIdx.x * 4 + wid; rt < ntiles; rt += gridDim.x * 4) {
        int row = rt * 16 + l15;
        f32x4 acc[8];
        #pragma unroll
        for (int nt = 0; nt < 8; ++nt) acc[nt] = (f32x4)(0.f);
        #pragma unroll
        for (int kt = 0; kt < 4; ++kt) {
            uint4 af = make_uint4(0u, 0u, 0u, 0u);
            if (row < N) {
                float4 xa = X4[(size_t)row * 32 + kt * 8 + lhi * 2];
                float4 xb = X4[(size_t)row * 32 + kt * 8 + lhi * 2 + 1];
                af.x = pack2bf(xa.x, xa.y); af.y = pack2bf(xa.z, xa.w);
                af.z = pack2bf(xb.x, xb.y); af.w = pack2bf(xb.z, xb.w);
            }
            short8 a = asfrag(af);
            #pragma unroll
            for (int nt = 0; nt < 8; ++nt)
                acc[nt] = mfma_bf16(a, asfrag(Bf[nt * 256 + kt * 64 + l]), acc[nt]);
        }
        #pragma unroll
        for (int r = 0; r < 4; ++r) {
            int orow = rt * 16 + lhi * 4 + r;
            if (orow < N) {
                #pragma unroll
                for (int nt = 0; nt < 8; ++nt)
                    hst[(size_t)orow * 128 + nt * 16 + l15] = f2bf(acc[nt][r] + bv[nt]);
            }
        }
    }
}

// ---------------------------------------------------------------------------
// K2: per-node attention coefficients from bf16 h (memory-bound).
// ---------------------------------------------------------------------------
__global__ __launch_bounds__(256) void alpha_kernel(
    const unsigned* __restrict__ hbf,
    const float* __restrict__ ls0, const float* __restrict__ ld0,
    const float* __restrict__ ls1, const float* __restrict__ ld1,
    float* __restrict__ as0, float* __restrict__ ad0,
    float* __restrict__ as1, float* __restrict__ ad1, int N)
{
    __shared__ float lin[512];
    int t = threadIdx.x;
    for (int i = t; i < 128; i += 256) {
        lin[i] = ls0[i]; lin[128 + i] = ld0[i];
        lin[256 + i] = ls1[i]; lin[384 + i] = ld1[i];
    }
    __syncthreads();
    int idx = blockIdx.x * 256 + t;
    if (idx >= N * 8) return;
    int node = idx >> 3, head = idx & 7;
    const uint4* H = reinterpret_cast<const uint4*>(hbf);
    uint4 va = H[(size_t)node * 16 + head * 2];
    uint4 vb = H[(size_t)node * 16 + head * 2 + 1];
    float h[16];
    h[0] = bflo(va.x); h[1] = bfhi(va.x); h[2] = bflo(va.y); h[3] = bfhi(va.y);
    h[4] = bflo(va.z); h[5] = bfhi(va.z); h[6] = bflo(va.w); h[7] = bfhi(va.w);
    h[8] = bflo(vb.x); h[9] = bfhi(vb.x); h[10] = bflo(vb.y); h[11] = bfhi(vb.y);
    h[12] = bflo(vb.z); h[13] = bfhi(vb.z); h[14] = bflo(vb.w); h[15] = bfhi(vb.w);
    int base = head * 16;
    float d0 = 0.f, d1 = 0.f, d2 = 0.f, d3 = 0.f;
    #pragma unroll
    for (int d = 0; d < 16; ++d) {
        float hv = h[d];
        d0 = fmaf(hv, lin[base + d], d0);
        d1 = fmaf(hv, lin[128 + base + d], d1);
        d2 = fmaf(hv, lin[256 + base + d], d2);
        d3 = fmaf(hv, lin[384 + base + d], d3);
    }
    as0[idx] = d0; ad0[idx] = d1; as1[idx] = d2; ad1[idx] = d3;
}

// ---------------------------------------------------------------------------
// CSR build, XCD-region-aware + fused over both metapaths.
// ---------------------------------------------------------------------------
__global__ __launch_bounds__(256) void hist_fused(
    const int* __restrict__ ei0, int E0, int* __restrict__ deg0,
    const int* __restrict__ ei1, int E1, int* __restrict__ deg1, int rsize)
{
    int xg = blockIdx.x & 7;
    int mp = (blockIdx.x >> 3) & 1;
    int sub = blockIdx.x >> 4;            // [0,256)
    const int* ei = mp ? ei1 : ei0;
    int E = mp ? E1 : E0;
    int* deg = mp ? deg1 : deg0;
    const int stride = 256 * 256;
    for (int e = sub * 256 + threadIdx.x; e < E; e += stride) {
        int d = ei[E + e];
        if (d / rsize == xg) atomicAdd(&deg[d], 1);
    }
}

__global__ __launch_bounds__(256) void fill_fused(
    const int* __restrict__ ei0, int E0, const int* __restrict__ off0,
    int* __restrict__ cur0, int* __restrict__ perm0,
    const int* __restrict__ ei1, int E1, const int* __restrict__ off1,
    int* __restrict__ cur1, int* __restrict__ perm1, int rsize)
{
    int xg = blockIdx.x & 7;
    int mp = (blockIdx.x >> 3) & 1;
    int sub = blockIdx.x >> 4;            // [0,256)
    const int* ei = mp ? ei1 : ei0;
    int E = mp ? E1 : E0;
    const int* off = mp ? off1 : off0;
    int* cur = mp ? cur1 : cur0;
    int* perm = mp ? perm1 : perm0;
    const int stride = 256 * 256;
    for (int e = sub * 256 + threadIdx.x; e < E; e += stride) {
        int d = ei[E + e];
        if (d / rsize == xg) {
            int s = ei[e];
            int p = atomicAdd(&cur[d], 1);
            perm[off[d] + p] = s;
        }
    }
}

// ---------------------------------------------------------------------------
// Scans (fused over both metapaths).
// ---------------------------------------------------------------------------
__global__ __launch_bounds__(256) void scan1_fused(
    const int* __restrict__ in0, int* __restrict__ out0,
    const int* __restrict__ in1, int* __restrict__ out1,
    int* __restrict__ bsums, int n, int nb)
{
    __shared__ int sh[256];
    int mp = (blockIdx.x >= (unsigned)nb);
    int blk = blockIdx.x - (mp ? nb : 0);
    const int* in = mp ? in1 : in0;
    int* out = mp ? out1 : out0;
    int t = threadIdx.x;
    int i = blk * 256 + t;
    int v = (i < n) ? in[i] : 0;
    sh[t] = v;
    __syncthreads();
    for (int ofs = 1; ofs < 256; ofs <<= 1) {
        int xv = (t >= ofs) ? sh[t - ofs] : 0;
        __syncthreads();
        sh[t] += xv;
        __syncthreads();
    }
    if (i < n) out[i] = sh[t] - v;          // exclusive
    if (t == 255) bsums[mp * 512 + blk] = sh[255];
}

__global__ __launch_bounds__(512) void scan2_fused(int* __restrict__ bs, int nb)
{
    __shared__ int sh[512];
    int t = threadIdx.x;
    int* b = bs + blockIdx.x * 512;
    int v = (t < nb) ? b[t] : 0;
    sh[t] = v;
    __syncthreads();
    for (int ofs = 1; ofs < 512; ofs <<= 1) {
        int xv = (t >= ofs) ? sh[t - ofs] : 0;
        __syncthreads();
        sh[t] += xv;
        __syncthreads();
    }
    if (t < nb) b[t] = sh[t] - v;          // exclusive
}

__global__ __launch_bounds__(256) void scan3_fused(
    int* __restrict__ out0, int* __restrict__ out1,
    const int* __restrict__ bs, int n, int nb)
{
    int mp = (blockIdx.x >= (unsigned)nb);
    int blk = blockIdx.x - (mp ? nb : 0);
    int* out = mp ? out1 : out0;
    int i = blk * 256 + threadIdx.x;
    if (i < n) out[i] += bs[mp * 512 + blk];
}

// ---------------------------------------------------------------------------
// K3: per-destination aggregation (fused mp0+mp1), lane-specialized weights.
// One 64-lane wave per (mp, node); lane owns dims {2*lane, 2*lane+1}.
// Per 8-edge batch: lane l computes the softmax weight for (edge l&7,
// head l>>3) ONCE (8x less exp/lrelu work than all-lanes-redundant), then
// weights are redistributed via ds_bpermute (LDS pipe, off the VALU) and
// source ids via broadcast shuffle. hbf gather addresses depend only on the
// fast perm load, so 8 gathers stay in flight per batch.
// Tail: index clamped to 'start' (safe addr), weight forced to 0.
// ---------------------------------------------------------------------------
__global__ __launch_bounds__(256) void agg_fused(
    const int* __restrict__ off0, const int* __restrict__ perm0,
    const float* __restrict__ as0, const float* __restrict__ ad0,
    const int* __restrict__ off1, const int* __restrict__ perm1,
    const float* __restrict__ as1, const float* __restrict__ ad1,
    const unsigned* __restrict__ hbf,
    unsigned* __restrict__ o0, unsigned* __restrict__ o1, int N)
{
    int mp = blockIdx.x & 1;
    int wid = (blockIdx.x >> 1) * 4 + (threadIdx.x >> 6);
    int lane = threadIdx.x & 63;
    if (wid >= N) return;
    const int* off = mp ? off1 : off0;
    const int* perm = mp ? perm1 : perm0;
    const float* asrc = mp ? as1 : as0;
    const float* adst = mp ? ad1 : ad0;
    unsigned* outm = mp ? o1 : o0;
    int start = off[wid], end = off[wid + 1];
    int h2 = lane >> 3;            // head: owns dims AND weight computation
    int esel = lane & 7;           // edge slot this lane computes weight for
    int wsrc = lane & 56;          // shuffle base: lane (wsrc|k) holds w[k][h2]
    float av = adst[wid * 8 + h2];
    float p0 = 0.f, p1 = 0.f, q0 = 0.f, q1 = 0.f;
    float sA = 0.f, sB = 0.f;
    for (int i = start; i < end; i += 8) {
        int idx = i + esel;
        int sm = perm[idx < end ? idx : start];
        float alv = asrc[sm * 8 + h2] + av;
        alv = alv > 0.f ? alv : NEG * alv;
        float wm = (idx < end) ? __expf(alv) : 0.f;
        #pragma unroll
        for (int k = 0; k < 8; ++k) {
            int sk = __shfl(sm, k);                 // perm[i+k]
            float wk = __shfl(wm, wsrc | k);        // weight for (edge k, h2)
            unsigned u = hbf[(unsigned)(sk * 64) + lane];
            if (k & 1) {
                q0 = fmaf(bflo(u), wk, q0);
                q1 = fmaf(bfhi(u), wk, q1);
                sB += wk;
            } else {
                p0 = fmaf(bflo(u), wk, p0);
                p1 = fmaf(bfhi(u), wk, p1);
                sA += wk;
            }
        }
    }
    float acc0 = p0 + q0, acc1 = p1 + q1, ssum = sA + sB;
    float inv = 1.f / (ssum + 1e-16f);
    acc0 *= inv; acc1 *= inv;
    acc0 = acc0 > 0.f ? acc0 : 0.f;   // relu
    acc1 = acc1 > 0.f ? acc1 : 0.f;
    outm[(size_t)wid * 64 + lane] = pack2bf(acc0, acc1);
}

// ---------------------------------------------------------------------------
// K4: semantic-attention scores via MFMA over bf16 out0/out1.
// ---------------------------------------------------------------------------
__global__ __launch_bounds__(256) void score_mfma(
    const unsigned* __restrict__ o0, const unsigned* __restrict__ o1,
    const uint4* __restrict__ bfg, const float* __restrict__ kb,
    const float* __restrict__ q, float* __restrict__ partials, int N)
{
    __shared__ uint4 Bf[2048];   // 32 KB (k_w fragments)
    __shared__ float kbs[128], qs[128];
    __shared__ float red[2];
    int t = threadIdx.x;
    for (int i = t; i < 2048; i += 256) Bf[i] = bfg[i];
    if (t < 128) { kbs[t] = kb[t]; qs[t] = q[t]; }
    if (t < 2) red[t] = 0.f;
    __syncthreads();
    int wid = t >> 6, l = t & 63, l15 = l & 15, lhi = l >> 4;
    float qv[8], kbv[8];
    #pragma unroll
    for (int nt = 0; nt < 8; ++nt) {
        qv[nt] = qs[nt * 16 + l15];
        kbv[nt] = kbs[nt * 16 + l15];
    }
    int ntiles = (N + 15) >> 4;
    int ttiles = 2 * ntiles;
    const uint4* A0 = reinterpret_cast<const uint4*>(o0);
    const uint4* A1 = reinterpret_cast<const uint4*>(o1);
    for (int tid = blockIdx.x * 4 + wid; tid < ttiles; tid += gridDim.x * 4) {
        int m = (tid >= ntiles);
        int rt = tid - (m ? ntiles : 0);
        const uint4* A = m ? A1 : A0;
        int row = rt * 16 + l15;
        f32x4 acc[8];
        #pragma unroll
        for (int nt = 0; nt < 8; ++nt) acc[nt] = (f32x4)(0.f);
        #pragma unroll
        for (int kt = 0; kt < 4; ++kt) {
            uint4 av = (row < N) ? A[(size_t)row * 16 + kt * 4 + lhi]
                                 : make_uint4(0u, 0u, 0u, 0u);
            short8 a = asfrag(av);
            #pragma unroll
            for (int nt = 0; nt < 8; ++nt)
                acc[nt] = mfma_bf16(a, asfrag(Bf[nt * 256 + kt * 64 + l]), acc[nt]);
        }
        float partial = 0.f;
        int rbase = rt * 16 + lhi * 4;
        #pragma unroll
        for (int r = 0; r < 4; ++r) {
            if (rbase + r < N) {
                #pragma unroll
                for (int nt = 0; nt < 8; ++nt)
                    partial += qv[nt] * tanh_fast(acc[nt][r] + kbv[nt]);
            }
        }
        partial += __shfl_xor(partial, 1);
        partial += __shfl_xor(partial, 2);
        partial += __shfl_xor(partial, 4);
        partial += __shfl_xor(partial, 8);
        partial += __shfl_xor(partial, 16);
        partial += __shfl_xor(partial, 32);
        if (l == 0) atomicAdd(&red[m], partial);
    }
    __syncthreads();
    if (t < 2) partials[blockIdx.x * 2 + t] = red[t];
}

__global__ __launch_bounds__(256) void beta_kernel(
    const float* __restrict__ partials, int G, float invN, float* __restrict__ beta)
{
    __shared__ float r0[256], r1[256];
    int t = threadIdx.x;
    float s0 = 0.f, s1 = 0.f;
    for (int i = t; i < G; i += 256) { s0 += partials[i * 2]; s1 += partials[i * 2 + 1]; }
    r0[t] = s0; r1[t] = s1; __syncthreads();
    for (int o = 128; o > 0; o >>= 1) {
        if (t < o) { r0[t] += r0[t + o]; r1[t] += r1[t + o]; }
        __syncthreads();
    }
    if (t == 0) {
        float a = r0[0] * invN, b = r1[0] * invN;
        float mx = fmaxf(a, b);
        float ea = __expf(a - mx), eb = __expf(b - mx);
        float inv = 1.f / (ea + eb);
        beta[0] = ea * inv; beta[1] = eb * inv;
    }
}

// ---------------------------------------------------------------------------
// K6: y = (b0*out0 + b1*out1) @ out_w + out_b via MFMA (f32 output).
// ---------------------------------------------------------------------------
__global__ __launch_bounds__(256) void final_mfma(
    const unsigned* __restrict__ o0, const unsigned* __restrict__ o1,
    const uint4* __restrict__ bfg, const float* __restrict__ ob,
    const float* __restrict__ beta, float* __restrict__ y, int N)
{
    __shared__ uint4 Bf[1024];   // 16 KB (out_w fragments)
    __shared__ float obs[64];
    int t = threadIdx.x;
    for (int i = t; i < 1024; i += 256) Bf[i] = bfg[i];
    if (t < 64) obs[t] = ob[t];
    __syncthreads();
    float b0 = beta[0], b1 = beta[1];
    int wid = t >> 6, l = t & 63, l15 = l & 15, lhi = l >> 4;
    float obv[4];
    #pragma unroll
    for (int nt = 0; nt < 4; ++nt) obv[nt] = obs[nt * 16 + l15];
    int ntiles = (N + 15) >> 4;
    const uint4* A0 = reinterpret_cast<const uint4*>(o0);
    const uint4* A1 = reinterpret_cast<const uint4*>(o1);
    for (int rt = blockIdx.x * 4 + wid; rt < ntiles; rt += gridDim.x * 4) {
        int row = rt * 16 + l15;
        f32x4 acc[4];
        #pragma unroll
        for (int nt = 0; nt < 4; ++nt) acc[nt] = (f32x4)(0.f);
        #pragma unroll
        for (int kt = 0; kt < 4; ++kt) {
            uint4 af = make_uint4(0u, 0u, 0u, 0u);
            if (row < N) {
                uint4 a0 = A0[(size_t)row * 16 + kt * 4 + lhi];
                uint4 a1 = A1[(size_t)row * 16 + kt * 4 + lhi];
                af.x = pack2bf(b0 * bflo(a0.x) + b1 * bflo(a1.x),
                               b0 * bfhi(a0.x) + b1 * bfhi(a1.x));
                af.y = pack2bf(b0 * bflo(a0.y) + b1 * bflo(a1.y),
                               b0 * bfhi(a0.y) + b1 * bfhi(a1.y));
                af.z = pack2bf(b0 * bflo(a0.z) + b1 * bflo(a1.z),
                               b0 * bfhi(a0.z) + b1 * bfhi(a1.z));
                af.w = pack2bf(b0 * bflo(a0.w) + b1 * bflo(a1.w),
                               b0 * bfhi(a0.w) + b1 * bfhi(a1.w));
            }
            short8 a = asfrag(af);
            #pragma unroll
            for (int nt = 0; nt < 4; ++nt)
                acc[nt] = mfma_bf16(a, asfrag(Bf[nt * 256 + kt * 64 + l]), acc[nt]);
        }
        #pragma unroll
        for (int r = 0; r < 4; ++r) {
            int orow = rt * 16 + lhi * 4 + r;
            if (orow < N) {
                #pragma unroll
                for (int nt = 0; nt < 4; ++nt)
                    y[(size_t)orow * 64 + nt * 16 + l15] = acc[nt][r] + obv[nt];
            }
        }
    }
}

// ---------------------------------------------------------------------------
extern "C" void kernel_launch(void* const* d_in, const int* in_sizes, int n_in,
                              void* d_out, int out_size, void* d_ws, size_t ws_size,
                              hipStream_t stream)
{
    const float* x   = (const float*)d_in[0];
    const int*   ei0 = (const int*)d_in[1];
    const int*   ei1 = (const int*)d_in[2];
    const float* pw  = (const float*)d_in[3];
    const float* pb  = (const float*)d_in[4];
    const float* ls0 = (const float*)d_in[5];
    const float* ld0 = (const float*)d_in[6];
    const float* ls1 = (const float*)d_in[7];
    const float* ld1 = (const float*)d_in[8];
    const float* kw  = (const float*)d_in[9];
    const float* kb  = (const float*)d_in[10];
    const float* q   = (const float*)d_in[11];
    const float* ow  = (const float*)d_in[12];
    const float* ob  = (const float*)d_in[13];
    int N  = in_sizes[0] / 128;
    int E0 = in_sizes[1] / 2;
    int E1 = in_sizes[2] / 2;

    char* w = (char*)d_ws;
    size_t o = 0;
    auto alloc = [&](size_t bytes) -> void* {
        void* p = w + o;
        o += (bytes + 255) & ~(size_t)255;
        return p;
    };
    unsigned* hbf  = (unsigned*)alloc((size_t)N * 128 * 2);   // bf16 h
    float* as0  = (float*)alloc((size_t)N * 8 * 4);
    float* ad0  = (float*)alloc((size_t)N * 8 * 4);
    float* as1  = (float*)alloc((size_t)N * 8 * 4);
    float* ad1  = (float*)alloc((size_t)N * 8 * 4);
    unsigned* out0 = (unsigned*)alloc((size_t)N * 128 * 2);   // bf16 out
    unsigned* out1 = (unsigned*)alloc((size_t)N * 128 * 2);
    char*  zbase = w + o;                       // contiguous zeroed region
    int* deg0 = (int*)alloc((size_t)(N + 1) * 4);
    int* cur0 = (int*)alloc((size_t)N * 4);
    int* deg1 = (int*)alloc((size_t)(N + 1) * 4);
    int* cur1 = (int*)alloc((size_t)N * 4);
    size_t zbytes = (w + o) - zbase;
    int* off0 = (int*)alloc((size_t)(N + 1) * 4);
    int* off1 = (int*)alloc((size_t)(N + 1) * 4);
    int* bsums = (int*)alloc(1024 * 4);
    int* perm0 = (int*)alloc((size_t)E0 * 4);
    int* perm1 = (int*)alloc((size_t)E1 * 4);
    float* partials = (float*)alloc((size_t)2 * 2048 * 4);
    float* beta = (float*)alloc(256);
    uint4* bfpw = (uint4*)alloc(2048 * 16);
    uint4* bfkw = (uint4*)alloc(2048 * 16);
    uint4* bfow = (uint4*)alloc(1024 * 16);

    int rsize = (N + 7) / 8;   // dst-region size for XCD ownership

    hipMemsetAsync(zbase, 0, zbytes, stream);

    prep_bfrag<<<3, 256, 0, stream>>>(pw, kw, ow, bfpw, bfkw, bfow);

    proj_mfma<<<512, 256, 0, stream>>>(x, bfpw, pb, (unsigned short*)hbf, N);

    int ablocks = (N * 8 + 255) / 256;
    alpha_kernel<<<ablocks, 256, 0, stream>>>(hbf, ls0, ld0, ls1, ld1,
                                              as0, ad0, as1, ad1, N);

    hist_fused<<<4096, 256, 0, stream>>>(ei0, E0, deg0, ei1, E1, deg1, rsize);

    int n1 = N + 1;
    int nb = (n1 + 255) / 256;   // must be <= 512
    scan1_fused<<<2 * nb, 256, 0, stream>>>(deg0, off0, deg1, off1, bsums, n1, nb);
    scan2_fused<<<2, 512, 0, stream>>>(bsums, nb);
    scan3_fused<<<2 * nb, 256, 0, stream>>>(off0, off1, bsums, n1, nb);

    fill_fused<<<4096, 256, 0, stream>>>(ei0, E0, off0, cur0, perm0,
                                         ei1, E1, off1, cur1, perm1, rsize);

    int aggBlocks = 2 * ((N + 3) / 4);
    agg_fused<<<aggBlocks, 256, 0, stream>>>(off0, perm0, as0, ad0,
                                             off1, perm1, as1, ad1,
                                             hbf, out0, out1, N);

    const int SG = 512;
    score_mfma<<<SG, 256, 0, stream>>>(out0, out1, bfkw, kb, q, partials, N);
    beta_kernel<<<1, 256, 0, stream>>>(partials, SG, 1.0f / (float)N, beta);
    final_mfma<<<512, 256, 0, stream>>>(out0, out1, bfow, ob, beta, (float*)d_out, N);
}